// Round 6
// baseline (238.266 us; speedup 1.0000x reference)
//
#include <hip/hip_runtime.h>
#include <hip/hip_bf16.h>

#define B_ 2
#define S_ 2048
#define D_ 1024
#define H_ 16
#define DKV_ 64
#define INNER_ 1024
#define M_ (B_*S_)   // 4096

typedef unsigned short ushort_t;
typedef unsigned int u32;
typedef __bf16 bf16x8 __attribute__((ext_vector_type(8)));
typedef __bf16 bf16x4 __attribute__((ext_vector_type(4)));
typedef float f32x4 __attribute__((ext_vector_type(4)));

#define VMCNT0 asm volatile("s_waitcnt vmcnt(0)" ::: "memory")
#define LOG2E 1.4426950408889634f

__device__ __forceinline__ unsigned short f2bf(float f) {
    unsigned int u = __builtin_bit_cast(unsigned int, f);
    unsigned int r = (u + 0x7fffu + ((u >> 16) & 1u)) >> 16;
    return (unsigned short)r;
}

__device__ __forceinline__ void gload16(const ushort_t* g, ushort_t* l) {
    __builtin_amdgcn_global_load_lds(
        (const __attribute__((address_space(1))) u32*)g,
        (__attribute__((address_space(3))) u32*)l, 16, 0, 0);
}

// ---------------- fp32 -> bf16 convert ----------------
__global__ __launch_bounds__(256) void cvt_bf16(const float* __restrict__ in,
                                                unsigned short* __restrict__ out, int n) {
    int i = (blockIdx.x * 256 + threadIdx.x) * 4;
    if (i < n) {
        float4 v = *(const float4*)&in[i];
        ushort4 o;
        o.x = f2bf(v.x); o.y = f2bf(v.y); o.z = f2bf(v.z); o.w = f2bf(v.w);
        *(ushort4*)&out[i] = o;
    }
}

// ---------------- transpose+convert weights: Wt[n][k] = (bf16)W[k][n] ----------------
__global__ __launch_bounds__(256) void transp_bf16(
        const float* __restrict__ s0, const float* __restrict__ s1,
        const float* __restrict__ s2, const float* __restrict__ s3,
        unsigned short* __restrict__ d0, unsigned short* __restrict__ d1,
        unsigned short* __restrict__ d2, unsigned short* __restrict__ d3) {
    const float* srcs[4] = {s0, s1, s2, s3};
    unsigned short* dsts[4] = {d0, d1, d2, d3};
    const float* src = srcs[blockIdx.z];
    unsigned short* dst = dsts[blockIdx.z];
    __shared__ float t[64][65];
    int k0 = blockIdx.y * 64, n0 = blockIdx.x * 64;
    for (int i = threadIdx.x; i < 4096; i += 256) {
        int r = i >> 6, c = i & 63;
        t[r][c] = src[(k0 + r) * 1024 + n0 + c];
    }
    __syncthreads();
    for (int i = threadIdx.x; i < 4096; i += 256) {
        int r = i >> 6, c = i & 63;
        dst[(n0 + r) * 1024 + k0 + c] = f2bf(t[c][r]);
    }
}

// ---------------- T5 relative bias table, pre-scaled by log2e ----------------
__global__ __launch_bounds__(256) void bias_kernel(const float* __restrict__ rb,
                                                   float* __restrict__ btab) {
    int idx = blockIdx.x * 256 + threadIdx.x;   // 0..65535
    int h = idx >> 12, pos = idx & 4095;
    int rel = pos - 2048;
    int bb = rel > 0 ? 16 : 0;
    int rp = rel < 0 ? -rel : rel;
    int bucket;
    if (rp < 8) bucket = bb + rp;
    else {
        int v = 8 + (int)(logf((float)rp * 0.125f) / 2.7725887f * 8.0f);
        bucket = bb + (v < 15 ? v : 15);
    }
    btab[idx] = rb[bucket * 16 + h] * LOG2E;
}

// ---------------- fused QKV GEMM: A[4096][1024] x {WQ,WK,WV}^T, 128x128 tile, BK=64 ----------------
__global__ __launch_bounds__(256) void gemm_qkv(const ushort_t* __restrict__ A,
        const ushort_t* __restrict__ WQ, const ushort_t* __restrict__ WK, const ushort_t* __restrict__ WV,
        ushort_t* __restrict__ Qb, ushort_t* __restrict__ Kb, ushort_t* __restrict__ Vtb) {
    __shared__ alignas(16) ushort_t As[128][64];
    __shared__ alignas(16) ushort_t Bs[128][64];
    int tid = threadIdx.x, wid = tid >> 6, lane = tid & 63;
    int linear = blockIdx.x;                    // 768 blocks
    int swz = (linear & 7) * 96 + (linear >> 3);
    int m0 = (swz / 24) * 128;
    int nblk = swz % 24;
    int sel = nblk >> 3;                        // 0=Q 1=K 2=V
    const ushort_t* Bt = sel == 0 ? WQ : (sel == 1 ? WK : WV);
    int n0 = (nblk & 7) * 128;
    int lr = lane & 15, lg = lane >> 4;
    int wm = (wid >> 1) * 64, wn = (wid & 1) * 64;
    int srow = tid >> 3, sp = tid & 7;
    int scol = (sp ^ (srow & 7)) * 8;           // pre-swizzled source column
    int cR0 = (lg ^ (lr & 7)) * 8;              // swizzled read cols, halves 0/1
    int cR1 = ((4 + lg) ^ (lr & 7)) * 8;
    const ushort_t* Abase = A + (size_t)m0 * 1024 + scol;
    const ushort_t* Bbase = Bt + (size_t)n0 * 1024 + scol;
    f32x4 acc[4][4] = {};
    for (int kt = 0; kt < 1024; kt += 64) {
        #pragma unroll
        for (int j = 0; j < 4; ++j) {
            int row = j * 32 + srow;
            gload16(Abase + row * 1024 + kt, &As[0][0] + (j * 256 + tid) * 8);
            gload16(Bbase + row * 1024 + kt, &Bs[0][0] + (j * 256 + tid) * 8);
        }
        VMCNT0;
        __syncthreads();
        bf16x8 af[4][2], bfr[4][2];
        #pragma unroll
        for (int t = 0; t < 4; ++t) {
            af[t][0]  = *(const bf16x8*)&As[wm + t * 16 + lr][cR0];
            af[t][1]  = *(const bf16x8*)&As[wm + t * 16 + lr][cR1];
            bfr[t][0] = *(const bf16x8*)&Bs[wn + t * 16 + lr][cR0];
            bfr[t][1] = *(const bf16x8*)&Bs[wn + t * 16 + lr][cR1];
        }
        #pragma unroll
        for (int hh = 0; hh < 2; ++hh)
            #pragma unroll
            for (int i2 = 0; i2 < 4; ++i2)
                #pragma unroll
                for (int j2 = 0; j2 < 4; ++j2)
                    acc[i2][j2] = __builtin_amdgcn_mfma_f32_16x16x32_bf16(af[i2][hh], bfr[j2][hh], acc[i2][j2], 0, 0, 0);
        __syncthreads();
    }
    #pragma unroll
    for (int i2 = 0; i2 < 4; ++i2)
        #pragma unroll
        for (int j2 = 0; j2 < 4; ++j2) {
            int col = n0 + wn + j2 * 16 + lr;
            int hh = col >> 6, d = col & 63;
            if (sel < 2) {
                ushort_t* dst = sel == 0 ? Qb : Kb;
                #pragma unroll
                for (int r = 0; r < 4; ++r) {
                    int row = m0 + wm + i2 * 16 + lg * 4 + r;
                    int b = row >> 11, s = row & 2047;
                    dst[(((size_t)(b * H_ + hh) * S_ + s)) * DKV_ + d] = f2bf(acc[i2][j2][r]);
                }
            } else {
                int row0 = m0 + wm + i2 * 16 + lg * 4;
                int b = row0 >> 11, s0 = row0 & 2047;
                ushort4 sv;
                sv.x = f2bf(acc[i2][j2][0]); sv.y = f2bf(acc[i2][j2][1]);
                sv.z = f2bf(acc[i2][j2][2]); sv.w = f2bf(acc[i2][j2][3]);
                *(ushort4*)&Vtb[((size_t)(b * H_ + hh) * DKV_ + d) * S_ + s0] = sv;
            }
        }
}

// ---------------- output projection GEMM: 64x128 tile, BK=64, fp32 out ----------------
__global__ __launch_bounds__(256) void gemm_out(const ushort_t* __restrict__ A,
                                                const ushort_t* __restrict__ Bt,
                                                float* __restrict__ C) {
    __shared__ alignas(16) ushort_t As[64][64];
    __shared__ alignas(16) ushort_t Bs[128][64];
    int tid = threadIdx.x, wid = tid >> 6, lane = tid & 63;
    int linear = blockIdx.x;                    // 512 blocks
    int swz = (linear & 7) * 64 + (linear >> 3);
    int m0 = (swz >> 3) * 64, n0 = (swz & 7) * 128;
    int lr = lane & 15, lg = lane >> 4;
    int wn = wid * 32;
    int srow = tid >> 3, sp = tid & 7;
    int scol = (sp ^ (srow & 7)) * 8;
    int cR0 = (lg ^ (lr & 7)) * 8;
    int cR1 = ((4 + lg) ^ (lr & 7)) * 8;
    const ushort_t* Abase = A + (size_t)m0 * 1024 + scol;
    const ushort_t* Bbase = Bt + (size_t)n0 * 1024 + scol;
    f32x4 acc[4][2] = {};
    for (int kt = 0; kt < 1024; kt += 64) {
        #pragma unroll
        for (int j = 0; j < 2; ++j) {
            int row = j * 32 + srow;
            gload16(Abase + row * 1024 + kt, &As[0][0] + (j * 256 + tid) * 8);
        }
        #pragma unroll
        for (int j = 0; j < 4; ++j) {
            int row = j * 32 + srow;
            gload16(Bbase + row * 1024 + kt, &Bs[0][0] + (j * 256 + tid) * 8);
        }
        VMCNT0;
        __syncthreads();
        bf16x8 af[4][2], bfr[2][2];
        #pragma unroll
        for (int t = 0; t < 4; ++t) {
            af[t][0] = *(const bf16x8*)&As[t * 16 + lr][cR0];
            af[t][1] = *(const bf16x8*)&As[t * 16 + lr][cR1];
        }
        #pragma unroll
        for (int j = 0; j < 2; ++j) {
            bfr[j][0] = *(const bf16x8*)&Bs[wn + j * 16 + lr][cR0];
            bfr[j][1] = *(const bf16x8*)&Bs[wn + j * 16 + lr][cR1];
        }
        #pragma unroll
        for (int hh = 0; hh < 2; ++hh)
            #pragma unroll
            for (int i2 = 0; i2 < 4; ++i2)
                #pragma unroll
                for (int j2 = 0; j2 < 2; ++j2)
                    acc[i2][j2] = __builtin_amdgcn_mfma_f32_16x16x32_bf16(af[i2][hh], bfr[j2][hh], acc[i2][j2], 0, 0, 0);
        __syncthreads();
    }
    #pragma unroll
    for (int i2 = 0; i2 < 4; ++i2)
        #pragma unroll
        for (int j2 = 0; j2 < 2; ++j2)
            #pragma unroll
            for (int r = 0; r < 4; ++r)
                C[(size_t)(m0 + i2 * 16 + lg * 4 + r) * 1024 + n0 + wn + j2 * 16 + lr] = acc[i2][j2][r];
}

// ---------------- flash attention v3: K in 3-buf LDS, V in register dbuf (1 tile ahead) ----------------
struct VTile { bf16x8 f[4][2]; };

__global__ __launch_bounds__(256, 3) void flash_attn(const ushort_t* __restrict__ Q,
                                                     const ushort_t* __restrict__ Kg,
                                                     const ushort_t* __restrict__ Vt,
                                                     const float* __restrict__ bias_tab,
                                                     ushort_t* __restrict__ Out) {
    __shared__ alignas(16) ushort_t Ks[3][64][64];
    __shared__ alignas(16) ushort_t Ps[4][16][64];
    __shared__ float LbS[2176];
    int tid = threadIdx.x, wid = tid >> 6, lane = tid & 63;
    int linear = blockIdx.x;                 // 512 blocks
    int swz = (linear & 7) * 64 + (linear >> 3);
    int bh = swz >> 4, qblk = swz & 15;
    int h = bh & 15, b = bh >> 4;
    int q0b = qblk * 128;
    int q0w = q0b + wid * 32;                // this wave: q0w..q0w+31 (2 groups of 16)
    int lr = lane & 15, lg = lane >> 4;

    // bias slice
    {
        const float* bsrc = bias_tab + h * 4096 + 2048 - q0b - 127;
        for (int i = tid; i < 2175; i += 256) LbS[i] = bsrc[i];
    }

    // Q fragments, both groups
    const ushort_t* Qbase = Q + ((size_t)bh * S_ + q0w) * DKV_;
    bf16x8 qA0 = *(const bf16x8*)&Qbase[lr * DKV_ + lg * 8];
    bf16x8 qA1 = *(const bf16x8*)&Qbase[lr * DKV_ + 32 + lg * 8];
    bf16x8 qB0 = *(const bf16x8*)&Qbase[(16 + lr) * DKV_ + lg * 8];
    bf16x8 qB1 = *(const bf16x8*)&Qbase[(16 + lr) * DKV_ + 32 + lg * 8];

    // K staging geometry (pre-swizzled source)
    int srow = tid >> 3, sp = tid & 7;
    int kc = (sp ^ (srow & 7)) * 8;
    const ushort_t* Ksrc = Kg + (size_t)bh * S_ * DKV_ + kc;
    // V direct fragment base: row = bh*64 + dt*16 + lr, col = kt + lg*8 (+32)
    const ushort_t* Vfrag = Vt + ((size_t)bh * DKV_ + lr) * S_ + lg * 8;
    // swizzled K fragment-read columns
    int c0 = (lg ^ (lr & 7)) * 8;
    int c1 = ((4 + lg) ^ (lr & 7)) * 8;
    int pxor = (lr & 7) << 4;

    f32x4 oA[4] = {}, oB[4] = {};
    f32x4 lpA = {}, lpB = {};
    float mA = -INFINITY, mB = -INFINITY;
    const int bbA = 127 - wid * 32 + 4 * lg - lr;
    const int bbB = bbA - 16;

    auto stageK = [&](int bi, int kt) {
        ushort_t* kb = &Ks[bi][0][0];
        gload16(Ksrc + (size_t)(kt + srow) * 64,      kb + tid * 8);
        gload16(Ksrc + (size_t)(kt + 32 + srow) * 64, kb + 2048 + tid * 8);
    };
    auto loadV = [&](int kt, VTile& v) {
        #pragma unroll
        for (int dt = 0; dt < 4; ++dt) {
            const ushort_t* vp = Vfrag + (size_t)dt * 16 * S_ + kt;
            v.f[dt][0] = *(const bf16x8*)vp;
            v.f[dt][1] = *(const bf16x8*)(vp + 32);
        }
    };

    VTile vA, vB;
    // prologue: V(0) to regs, K(0),K(1) to LDS
    loadV(0, vA);
    stageK(0, 0);
    stageK(1, 64);
    asm volatile("s_waitcnt vmcnt(2)" ::: "memory");   // K(0) landed (K(1) may be in flight)
    __syncthreads();

    auto body = [&](int t, int cur, VTile& vuse, VTile& vnext) {
        const int kt = t * 64;
        if (t < 31) loadV(kt + 64, vnext);             // 8 global_load_dwordx4
        if (t < 30) {                                  // 2 global_load_lds
            int nb = cur + 2; if (nb >= 3) nb -= 3;
            stageK(nb, kt + 128);
        }
        __builtin_amdgcn_sched_barrier(0);             // pin load issue point
        // QK^T swapped: C[key][q], K fragments shared by both q-groups
        f32x4 sA[4] = {}, sB[4] = {};
        __builtin_amdgcn_s_setprio(1);
        #pragma unroll
        for (int nt = 0; nt < 4; ++nt) {
            bf16x8 kf0 = *(const bf16x8*)&Ks[cur][nt * 16 + lr][c0];
            bf16x8 kf1 = *(const bf16x8*)&Ks[cur][nt * 16 + lr][c1];
            sA[nt] = __builtin_amdgcn_mfma_f32_16x16x32_bf16(kf0, qA0, sA[nt], 0, 0, 0);
            sA[nt] = __builtin_amdgcn_mfma_f32_16x16x32_bf16(kf1, qA1, sA[nt], 0, 0, 0);
            sB[nt] = __builtin_amdgcn_mfma_f32_16x16x32_bf16(kf0, qB0, sB[nt], 0, 0, 0);
            sB[nt] = __builtin_amdgcn_mfma_f32_16x16x32_bf16(kf1, qB1, sB[nt], 0, 0, 0);
        }
        __builtin_amdgcn_s_setprio(0);
        char* pbase = (char*)&Ps[wid][lr][0];
        // ---- softmax A ----
        bf16x8 pfA0, pfA1;
        {
            float p[4][4]; float mnt[4];
            const int bi = kt + bbA;
            #pragma unroll
            for (int nt = 0; nt < 4; ++nt) {
                #pragma unroll
                for (int r = 0; r < 4; ++r)
                    p[nt][r] = fmaf(sA[nt][r], LOG2E, LbS[bi + nt * 16 + r]);
                mnt[nt] = fmaxf(fmaxf(p[nt][0], p[nt][1]), fmaxf(p[nt][2], p[nt][3]));
            }
            float mt = fmaxf(fmaxf(mnt[0], mnt[1]), fmaxf(mnt[2], mnt[3]));
            mt = fmaxf(mt, __shfl_xor(mt, 16));
            mt = fmaxf(mt, __shfl_xor(mt, 32));
            if (!__all(mt <= mA + 8.f)) {
                float mnew = fmaxf(mA, mt);
                float sc = __builtin_amdgcn_exp2f(mA - mnew);
                mA = mnew;
                lpA *= sc;
                #pragma unroll
                for (int dt = 0; dt < 4; ++dt) oA[dt] *= sc;
            }
            #pragma unroll
            for (int nt = 0; nt < 4; ++nt) {
                #pragma unroll
                for (int r = 0; r < 4; ++r) {
                    p[nt][r] = __builtin_amdgcn_exp2f(p[nt][r] - mA);
                    lpA[r] += p[nt][r];
                }
                bf16x4 pv;
                pv[0] = (__bf16)p[nt][0]; pv[1] = (__bf16)p[nt][1];
                pv[2] = (__bf16)p[nt][2]; pv[3] = (__bf16)p[nt][3];
                *(bf16x4*)(pbase + ((nt * 32 + lg * 8) ^ pxor)) = pv;
            }
            pfA0 = *(const bf16x8*)(pbase + ((lg * 16) ^ pxor));
            pfA1 = *(const bf16x8*)(pbase + ((64 + lg * 16) ^ pxor));
        }
        // ---- PV A (overlaps softmax B's VALU) ----
        __builtin_amdgcn_s_setprio(1);
        #pragma unroll
        for (int dt = 0; dt < 4; ++dt) {
            oA[dt] = __builtin_amdgcn_mfma_f32_16x16x32_bf16(vuse.f[dt][0], pfA0, oA[dt], 0, 0, 0);
            oA[dt] = __builtin_amdgcn_mfma_f32_16x16x32_bf16(vuse.f[dt][1], pfA1, oA[dt], 0, 0, 0);
        }
        __builtin_amdgcn_s_setprio(0);
        // ---- softmax B ----
        bf16x8 pfB0, pfB1;
        {
            float p[4][4]; float mnt[4];
            const int bi = kt + bbB;
            #pragma unroll
            for (int nt = 0; nt < 4; ++nt) {
                #pragma unroll
                for (int r = 0; r < 4; ++r)
                    p[nt][r] = fmaf(sB[nt][r], LOG2E, LbS[bi + nt * 16 + r]);
                mnt[nt] = fmaxf(fmaxf(p[nt][0], p[nt][1]), fmaxf(p[nt][2], p[nt][3]));
            }
            float mt = fmaxf(fmaxf(mnt[0], mnt[1]), fmaxf(mnt[2], mnt[3]));
            mt = fmaxf(mt, __shfl_xor(mt, 16));
            mt = fmaxf(mt, __shfl_xor(mt, 32));
            if (!__all(mt <= mB + 8.f)) {
                float mnew = fmaxf(mB, mt);
                float sc = __builtin_amdgcn_exp2f(mB - mnew);
                mB = mnew;
                lpB *= sc;
                #pragma unroll
                for (int dt = 0; dt < 4; ++dt) oB[dt] *= sc;
            }
            #pragma unroll
            for (int nt = 0; nt < 4; ++nt) {
                #pragma unroll
                for (int r = 0; r < 4; ++r) {
                    p[nt][r] = __builtin_amdgcn_exp2f(p[nt][r] - mB);
                    lpB[r] += p[nt][r];
                }
                bf16x4 pv;
                pv[0] = (__bf16)p[nt][0]; pv[1] = (__bf16)p[nt][1];
                pv[2] = (__bf16)p[nt][2]; pv[3] = (__bf16)p[nt][3];
                *(bf16x4*)(pbase + ((nt * 32 + lg * 8) ^ pxor)) = pv;
            }
            pfB0 = *(const bf16x8*)(pbase + ((lg * 16) ^ pxor));
            pfB1 = *(const bf16x8*)(pbase + ((64 + lg * 16) ^ pxor));
        }
        // ---- PV B ----
        __builtin_amdgcn_s_setprio(1);
        #pragma unroll
        for (int dt = 0; dt < 4; ++dt) {
            oB[dt] = __builtin_amdgcn_mfma_f32_16x16x32_bf16(vuse.f[dt][0], pfB0, oB[dt], 0, 0, 0);
            oB[dt] = __builtin_amdgcn_mfma_f32_16x16x32_bf16(vuse.f[dt][1], pfB1, oB[dt], 0, 0, 0);
        }
        __builtin_amdgcn_s_setprio(0);
        // tile end: make K(t+1) visible (counted waits; never drain in steady state)
        if (t < 30) {
            asm volatile("s_waitcnt vmcnt(10)" ::: "memory");   // after K(t+1): V 8 + K 2
            __syncthreads();
        } else if (t == 30) {
            asm volatile("s_waitcnt vmcnt(8)" ::: "memory");    // after K(31): V(31) 8
            __syncthreads();
        }
    };

    for (int tt = 0; tt < 32; tt += 2) {
        int c0i = tt % 3;
        int c1i = c0i + 1; if (c1i >= 3) c1i = 0;
        body(tt,     c0i, vA, vB);
        body(tt + 1, c1i, vB, vA);
    }

    // final cross-lane l reduction
    float lA = (lpA[0] + lpA[1]) + (lpA[2] + lpA[3]);
    lA += __shfl_xor(lA, 16); lA += __shfl_xor(lA, 32);
    float lB = (lpB[0] + lpB[1]) + (lpB[2] + lpB[3]);
    lB += __shfl_xor(lB, 16); lB += __shfl_xor(lB, 32);
    // epilogue group A
    {
        float linv = 1.f / lA;
        char* pbase = (char*)&Ps[wid][lr][0];
        #pragma unroll
        for (int dt = 0; dt < 4; ++dt) {
            bf16x4 ov;
            ov[0] = (__bf16)(oA[dt][0] * linv); ov[1] = (__bf16)(oA[dt][1] * linv);
            ov[2] = (__bf16)(oA[dt][2] * linv); ov[3] = (__bf16)(oA[dt][3] * linv);
            *(bf16x4*)(pbase + ((dt * 32 + lg * 8) ^ pxor)) = ov;
        }
        int row = lane >> 2, seg = lane & 3;
        int rxor = (row & 7) << 4;
        char* rbase = (char*)&Ps[wid][row][0];
        uint4 v0 = *(uint4*)(rbase + ((seg * 32) ^ rxor));
        uint4 v1 = *(uint4*)(rbase + ((seg * 32 + 16) ^ rxor));
        ushort_t* dst = Out + (size_t)(b * S_ + q0w + row) * INNER_ + h * DKV_ + seg * 16;
        *(uint4*)&dst[0] = v0;
        *(uint4*)&dst[8] = v1;
    }
    // epilogue group B
    {
        float linv = 1.f / lB;
        char* pbase = (char*)&Ps[wid][lr][0];
        #pragma unroll
        for (int dt = 0; dt < 4; ++dt) {
            bf16x4 ov;
            ov[0] = (__bf16)(oB[dt][0] * linv); ov[1] = (__bf16)(oB[dt][1] * linv);
            ov[2] = (__bf16)(oB[dt][2] * linv); ov[3] = (__bf16)(oB[dt][3] * linv);
            *(bf16x4*)(pbase + ((dt * 32 + lg * 8) ^ pxor)) = ov;
        }
        int row = lane >> 2, seg = lane & 3;
        int rxor = (row & 7) << 4;
        char* rbase = (char*)&Ps[wid][row][0];
        uint4 v0 = *(uint4*)(rbase + ((seg * 32) ^ rxor));
        uint4 v1 = *(uint4*)(rbase + ((seg * 32 + 16) ^ rxor));
        ushort_t* dst = Out + (size_t)(b * S_ + q0w + 16 + row) * INNER_ + h * DKV_ + seg * 16;
        *(uint4*)&dst[0] = v0;
        *(uint4*)&dst[8] = v1;
    }
}

extern "C" void kernel_launch(void* const* d_in, const int* in_sizes, int n_in,
                              void* d_out, int out_size, void* d_ws, size_t ws_size,
                              hipStream_t stream) {
    const float* hs = (const float*)d_in[0];
    const float* wq = (const float*)d_in[1];
    const float* wk = (const float*)d_in[2];
    const float* wv = (const float*)d_in[3];
    const float* wo = (const float*)d_in[4];
    const float* rb = (const float*)d_in[5];

    char* ws = (char*)d_ws;
    unsigned short* Abf = (unsigned short*)(ws);                 // 8 MB  [4096][1024]
    unsigned short* Wqt = (unsigned short*)(ws + (8u  << 20));   // 2 MB  [1024][1024]
    unsigned short* Wkt = (unsigned short*)(ws + (10u << 20));
    unsigned short* Wvt = (unsigned short*)(ws + (12u << 20));
    unsigned short* Wot = (unsigned short*)(ws + (14u << 20));
    unsigned short* Qb  = (unsigned short*)(ws + (16u << 20));   // 8 MB  [b][h][s][64]
    unsigned short* Kb  = (unsigned short*)(ws + (24u << 20));   // 8 MB
    unsigned short* Vtb = (unsigned short*)(ws + (32u << 20));   // 8 MB  [b][h][64][s]
    unsigned short* AOb = (unsigned short*)(ws + (40u << 20));   // 8 MB  [4096][1024]
    float*          Btab = (float*)(ws + (48u << 20));           // 256 KB [16][4096]

    cvt_bf16<<<4096, 256, 0, stream>>>(hs, Abf, M_ * D_);
    transp_bf16<<<dim3(16, 16, 4), 256, 0, stream>>>(wq, wk, wv, wo, Wqt, Wkt, Wvt, Wot);
    bias_kernel<<<256, 256, 0, stream>>>(rb, Btab);

    gemm_qkv<<<768, 256, 0, stream>>>(Abf, Wqt, Wkt, Wvt, Qb, Kb, Vtb);

    flash_attn<<<512, 256, 0, stream>>>(Qb, Kb, Vtb, Btab, AOb);

    gemm_out<<<512, 256, 0, stream>>>(AOb, Wot, (float*)d_out);
}

// Round 7
// 133.933 us; speedup vs baseline: 1.7790x; 1.7790x over previous
//
#include <hip/hip_runtime.h>
#include <hip/hip_bf16.h>

#define B_ 2
#define S_ 2048
#define D_ 1024
#define H_ 16
#define DKV_ 64
#define INNER_ 1024
#define M_ (B_*S_)   // 4096

typedef unsigned short ushort_t;
typedef unsigned int u32;
typedef __bf16 bf16x8 __attribute__((ext_vector_type(8)));
typedef __bf16 bf16x4 __attribute__((ext_vector_type(4)));
typedef float f32x4 __attribute__((ext_vector_type(4)));

#define VMCNT0 asm volatile("s_waitcnt vmcnt(0)" ::: "memory")
#define LOG2E 1.4426950408889634f

__device__ __forceinline__ unsigned short f2bf(float f) {
    unsigned int u = __builtin_bit_cast(unsigned int, f);
    unsigned int r = (u + 0x7fffu + ((u >> 16) & 1u)) >> 16;
    return (unsigned short)r;
}

__device__ __forceinline__ void gload16(const ushort_t* g, ushort_t* l) {
    __builtin_amdgcn_global_load_lds(
        (const __attribute__((address_space(1))) u32*)g,
        (__attribute__((address_space(3))) u32*)l, 16, 0, 0);
}

// ---------------- fused prep: cvt(hidden) + transpose(weights) + bias table ----------------
__global__ __launch_bounds__(256) void prep_kernel(
        const float* __restrict__ hs,
        const float* __restrict__ s0, const float* __restrict__ s1,
        const float* __restrict__ s2, const float* __restrict__ s3,
        const float* __restrict__ rb,
        unsigned short* __restrict__ Abf,
        unsigned short* __restrict__ d0, unsigned short* __restrict__ d1,
        unsigned short* __restrict__ d2, unsigned short* __restrict__ d3,
        float* __restrict__ btab) {
    int bid = blockIdx.x, tid = threadIdx.x;
    if (bid < 4096) {
        // fp32 -> bf16 convert, 4 elems/thread
        int i = (bid * 256 + tid) * 4;
        float4 v = *(const float4*)&hs[i];
        ushort4 o;
        o.x = f2bf(v.x); o.y = f2bf(v.y); o.z = f2bf(v.z); o.w = f2bf(v.w);
        *(ushort4*)&Abf[i] = o;
    } else if (bid < 5120) {
        // weight transpose+convert: Wt[n][k] = (bf16)W[k][n]
        int t = bid - 4096;
        int z = t >> 8, rem = t & 255;
        int k0 = ((rem >> 4) & 15) * 64, n0 = (rem & 15) * 64;
        const float* srcs[4] = {s0, s1, s2, s3};
        unsigned short* dsts[4] = {d0, d1, d2, d3};
        const float* src = srcs[z];
        unsigned short* dst = dsts[z];
        __shared__ float tbuf[64][65];
        for (int i = tid; i < 4096; i += 256) {
            int r = i >> 6, c = i & 63;
            tbuf[r][c] = src[(k0 + r) * 1024 + n0 + c];
        }
        __syncthreads();
        for (int i = tid; i < 4096; i += 256) {
            int r = i >> 6, c = i & 63;
            dst[(n0 + r) * 1024 + k0 + c] = f2bf(tbuf[c][r]);
        }
    } else {
        // T5 relative bias table, pre-scaled by log2e: btab[h][rel+2048]
        #pragma unroll
        for (int j = 0; j < 4; ++j) {
            int idx = (bid - 5120) * 1024 + j * 256 + tid;   // 0..65535
            int h = idx >> 12, pos = idx & 4095;
            int rel = pos - 2048;
            int bb = rel > 0 ? 16 : 0;
            int rp = rel < 0 ? -rel : rel;
            int bucket;
            if (rp < 8) bucket = bb + rp;
            else {
                int v = 8 + (int)(logf((float)rp * 0.125f) / 2.7725887f * 8.0f);
                bucket = bb + (v < 15 ? v : 15);
            }
            btab[idx] = rb[bucket * 16 + h] * LOG2E;
        }
    }
}

// ---------------- fused QKV GEMM: A[4096][1024] x {WQ,WK,WV}^T, 128x128 tile, BK=64 ----------------
__global__ __launch_bounds__(256) void gemm_qkv(const ushort_t* __restrict__ A,
        const ushort_t* __restrict__ WQ, const ushort_t* __restrict__ WK, const ushort_t* __restrict__ WV,
        ushort_t* __restrict__ Qb, ushort_t* __restrict__ Kb, ushort_t* __restrict__ Vtb) {
    __shared__ alignas(16) ushort_t As[128][64];
    __shared__ alignas(16) ushort_t Bs[128][64];
    int tid = threadIdx.x, wid = tid >> 6, lane = tid & 63;
    int linear = blockIdx.x;                    // 768 blocks
    int swz = (linear & 7) * 96 + (linear >> 3);
    int m0 = (swz / 24) * 128;
    int nblk = swz % 24;
    int sel = nblk >> 3;                        // 0=Q 1=K 2=V
    const ushort_t* Bt = sel == 0 ? WQ : (sel == 1 ? WK : WV);
    int n0 = (nblk & 7) * 128;
    int lr = lane & 15, lg = lane >> 4;
    int wm = (wid >> 1) * 64, wn = (wid & 1) * 64;
    int srow = tid >> 3, sp = tid & 7;
    int scol = (sp ^ (srow & 7)) * 8;           // pre-swizzled source column
    int cR0 = (lg ^ (lr & 7)) * 8;              // swizzled read cols, halves 0/1
    int cR1 = ((4 + lg) ^ (lr & 7)) * 8;
    const ushort_t* Abase = A + (size_t)m0 * 1024 + scol;
    const ushort_t* Bbase = Bt + (size_t)n0 * 1024 + scol;
    f32x4 acc[4][4] = {};
    for (int kt = 0; kt < 1024; kt += 64) {
        #pragma unroll
        for (int j = 0; j < 4; ++j) {
            int row = j * 32 + srow;
            gload16(Abase + row * 1024 + kt, &As[0][0] + (j * 256 + tid) * 8);
            gload16(Bbase + row * 1024 + kt, &Bs[0][0] + (j * 256 + tid) * 8);
        }
        VMCNT0;
        __syncthreads();
        bf16x8 af[4][2], bfr[4][2];
        #pragma unroll
        for (int t = 0; t < 4; ++t) {
            af[t][0]  = *(const bf16x8*)&As[wm + t * 16 + lr][cR0];
            af[t][1]  = *(const bf16x8*)&As[wm + t * 16 + lr][cR1];
            bfr[t][0] = *(const bf16x8*)&Bs[wn + t * 16 + lr][cR0];
            bfr[t][1] = *(const bf16x8*)&Bs[wn + t * 16 + lr][cR1];
        }
        #pragma unroll
        for (int hh = 0; hh < 2; ++hh)
            #pragma unroll
            for (int i2 = 0; i2 < 4; ++i2)
                #pragma unroll
                for (int j2 = 0; j2 < 4; ++j2)
                    acc[i2][j2] = __builtin_amdgcn_mfma_f32_16x16x32_bf16(af[i2][hh], bfr[j2][hh], acc[i2][j2], 0, 0, 0);
        __syncthreads();
    }
    #pragma unroll
    for (int i2 = 0; i2 < 4; ++i2)
        #pragma unroll
        for (int j2 = 0; j2 < 4; ++j2) {
            int col = n0 + wn + j2 * 16 + lr;
            int hh = col >> 6, d = col & 63;
            if (sel < 2) {
                ushort_t* dst = sel == 0 ? Qb : Kb;
                #pragma unroll
                for (int r = 0; r < 4; ++r) {
                    int row = m0 + wm + i2 * 16 + lg * 4 + r;
                    int b = row >> 11, s = row & 2047;
                    dst[(((size_t)(b * H_ + hh) * S_ + s)) * DKV_ + d] = f2bf(acc[i2][j2][r]);
                }
            } else {
                int row0 = m0 + wm + i2 * 16 + lg * 4;
                int b = row0 >> 11, s0 = row0 & 2047;
                ushort4 sv;
                sv.x = f2bf(acc[i2][j2][0]); sv.y = f2bf(acc[i2][j2][1]);
                sv.z = f2bf(acc[i2][j2][2]); sv.w = f2bf(acc[i2][j2][3]);
                *(ushort4*)&Vtb[((size_t)(b * H_ + hh) * DKV_ + d) * S_ + s0] = sv;
            }
        }
}

// ---------------- output projection GEMM: 64x128 tile, BK=64, fp32 out ----------------
__global__ __launch_bounds__(256) void gemm_out(const ushort_t* __restrict__ A,
                                                const ushort_t* __restrict__ Bt,
                                                float* __restrict__ C) {
    __shared__ alignas(16) ushort_t As[64][64];
    __shared__ alignas(16) ushort_t Bs[128][64];
    int tid = threadIdx.x, wid = tid >> 6, lane = tid & 63;
    int linear = blockIdx.x;                    // 512 blocks
    int swz = (linear & 7) * 64 + (linear >> 3);
    int m0 = (swz >> 3) * 64, n0 = (swz & 7) * 128;
    int lr = lane & 15, lg = lane >> 4;
    int wn = wid * 32;
    int srow = tid >> 3, sp = tid & 7;
    int scol = (sp ^ (srow & 7)) * 8;
    int cR0 = (lg ^ (lr & 7)) * 8;
    int cR1 = ((4 + lg) ^ (lr & 7)) * 8;
    const ushort_t* Abase = A + (size_t)m0 * 1024 + scol;
    const ushort_t* Bbase = Bt + (size_t)n0 * 1024 + scol;
    f32x4 acc[4][2] = {};
    for (int kt = 0; kt < 1024; kt += 64) {
        #pragma unroll
        for (int j = 0; j < 2; ++j) {
            int row = j * 32 + srow;
            gload16(Abase + row * 1024 + kt, &As[0][0] + (j * 256 + tid) * 8);
        }
        #pragma unroll
        for (int j = 0; j < 4; ++j) {
            int row = j * 32 + srow;
            gload16(Bbase + row * 1024 + kt, &Bs[0][0] + (j * 256 + tid) * 8);
        }
        VMCNT0;
        __syncthreads();
        bf16x8 af[4][2], bfr[2][2];
        #pragma unroll
        for (int t = 0; t < 4; ++t) {
            af[t][0] = *(const bf16x8*)&As[t * 16 + lr][cR0];
            af[t][1] = *(const bf16x8*)&As[t * 16 + lr][cR1];
        }
        #pragma unroll
        for (int j = 0; j < 2; ++j) {
            bfr[j][0] = *(const bf16x8*)&Bs[wn + j * 16 + lr][cR0];
            bfr[j][1] = *(const bf16x8*)&Bs[wn + j * 16 + lr][cR1];
        }
        #pragma unroll
        for (int hh = 0; hh < 2; ++hh)
            #pragma unroll
            for (int i2 = 0; i2 < 4; ++i2)
                #pragma unroll
                for (int j2 = 0; j2 < 2; ++j2)
                    acc[i2][j2] = __builtin_amdgcn_mfma_f32_16x16x32_bf16(af[i2][hh], bfr[j2][hh], acc[i2][j2], 0, 0, 0);
        __syncthreads();
    }
    #pragma unroll
    for (int i2 = 0; i2 < 4; ++i2)
        #pragma unroll
        for (int j2 = 0; j2 < 2; ++j2)
            #pragma unroll
            for (int r = 0; r < 4; ++r)
                C[(size_t)(m0 + i2 * 16 + lg * 4 + r) * 1024 + n0 + wn + j2 * 16 + lr] = acc[i2][j2][r];
}

// ---------------- flash attention v4: QBLK=128, 2-buf K/V, raw barriers, far-tile const bias ----------------
__global__ __launch_bounds__(256) void flash_attn(const ushort_t* __restrict__ Q,
                                                  const ushort_t* __restrict__ Kg,
                                                  const ushort_t* __restrict__ Vt,
                                                  const float* __restrict__ bias_tab,
                                                  ushort_t* __restrict__ Out) {
    __shared__ alignas(16) ushort_t Ks[2][64][64];
    __shared__ alignas(16) ushort_t Vs[2][64][64];
    __shared__ alignas(16) ushort_t Ps[4][16][64];
    __shared__ float LbS[2176];
    int tid = threadIdx.x, wid = tid >> 6, lane = tid & 63;
    int linear = blockIdx.x;                 // 512 blocks
    int swz = (linear & 7) * 64 + (linear >> 3);
    int bh = swz >> 4, qblk = swz & 15;
    int h = bh & 15, b = bh >> 4;
    int q0b = qblk * 128;
    int q0w = q0b + wid * 32;                // this wave: q0w..q0w+31 (2 groups of 16)
    int lr = lane & 15, lg = lane >> 4;

    // bias slice + saturated constants
    {
        const float* bsrc = bias_tab + h * 4096 + 2048 - q0b - 127;
        for (int i = tid; i < 2175; i += 256) LbS[i] = bsrc[i];
    }
    float cpos = bias_tab[h * 4096 + 4095];   // rel >= 128 (bucket 31)
    float cneg = bias_tab[h * 4096 + 0];      // rel <= -128 (bucket 15)

    // Q fragments, both groups
    const ushort_t* Qbase = Q + ((size_t)bh * S_ + q0w) * DKV_;
    bf16x8 qA0 = *(const bf16x8*)&Qbase[lr * DKV_ + lg * 8];
    bf16x8 qA1 = *(const bf16x8*)&Qbase[lr * DKV_ + 32 + lg * 8];
    bf16x8 qB0 = *(const bf16x8*)&Qbase[(16 + lr) * DKV_ + lg * 8];
    bf16x8 qB1 = *(const bf16x8*)&Qbase[(16 + lr) * DKV_ + 32 + lg * 8];

    // staging geometry (pre-swizzled source)
    int srow = tid >> 3, sp = tid & 7;
    int kc = (sp ^ (srow & 7)) * 8;
    const ushort_t* Ksrc = Kg + (size_t)bh * S_ * DKV_ + kc;
    const ushort_t* Vsrc = Vt + (size_t)bh * DKV_ * S_ + kc;
    // swizzled fragment-read columns
    int c0 = (lg ^ (lr & 7)) * 8;
    int c1 = ((4 + lg) ^ (lr & 7)) * 8;
    int pxor = (lr & 7) << 4;

    f32x4 oA[4] = {}, oB[4] = {};
    f32x4 lpA = {}, lpB = {};
    float mA = -INFINITY, mB = -INFINITY;
    const int bbA = 127 - wid * 32 + 4 * lg - lr;
    const int bbB = bbA - 16;

    auto stageK = [&](int bi, int kt) {
        ushort_t* kb = &Ks[bi][0][0];
        gload16(Ksrc + (size_t)(kt + srow) * 64,      kb + tid * 8);
        gload16(Ksrc + (size_t)(kt + 32 + srow) * 64, kb + 2048 + tid * 8);
    };
    auto stageV = [&](int bi, int kt) {
        ushort_t* vb = &Vs[bi][0][0];
        gload16(Vsrc + (size_t)srow * S_ + kt,        vb + tid * 8);
        gload16(Vsrc + (size_t)(32 + srow) * S_ + kt, vb + 2048 + tid * 8);
    };

    // prologue
    stageV(0, 0);
    stageK(0, 0);
    asm volatile("s_waitcnt vmcnt(0) lgkmcnt(0)" ::: "memory");
    __builtin_amdgcn_s_barrier();
    __builtin_amdgcn_sched_barrier(0);

    for (int t = 0; t < 32; ++t) {
        const int kt = t * 64;
        const int cur = t & 1;
        if (t < 31) { stageV(cur ^ 1, kt + 64); stageK(cur ^ 1, kt + 64); }
        // QK^T swapped: C[key][q], K fragments shared by both q-groups
        f32x4 sA[4] = {}, sB[4] = {};
        __builtin_amdgcn_s_setprio(1);
        #pragma unroll
        for (int nt = 0; nt < 4; ++nt) {
            bf16x8 kf0 = *(const bf16x8*)&Ks[cur][nt * 16 + lr][c0];
            bf16x8 kf1 = *(const bf16x8*)&Ks[cur][nt * 16 + lr][c1];
            sA[nt] = __builtin_amdgcn_mfma_f32_16x16x32_bf16(kf0, qA0, sA[nt], 0, 0, 0);
            sA[nt] = __builtin_amdgcn_mfma_f32_16x16x32_bf16(kf1, qA1, sA[nt], 0, 0, 0);
            sB[nt] = __builtin_amdgcn_mfma_f32_16x16x32_bf16(kf0, qB0, sB[nt], 0, 0, 0);
            sB[nt] = __builtin_amdgcn_mfma_f32_16x16x32_bf16(kf1, qB1, sB[nt], 0, 0, 0);
        }
        __builtin_amdgcn_s_setprio(0);
        // far tiles: bias is a uniform saturated constant (T5 buckets clamp at |rel|>=128)
        const bool far = (kt >= q0b + 256) || (kt + 64 <= q0b - 128);
        const float cb = (kt > q0b) ? cpos : cneg;
        char* pbase = (char*)&Ps[wid][lr][0];
        // ---- softmax A ----
        bf16x8 pfA0, pfA1;
        {
            float bb[4][4];
            if (far) {
                #pragma unroll
                for (int nt = 0; nt < 4; ++nt)
                    #pragma unroll
                    for (int r = 0; r < 4; ++r) bb[nt][r] = cb;
            } else {
                const int bi = kt + bbA;
                #pragma unroll
                for (int nt = 0; nt < 4; ++nt)
                    #pragma unroll
                    for (int r = 0; r < 4; ++r) bb[nt][r] = LbS[bi + nt * 16 + r];
            }
            float p[4][4]; float mnt[4];
            #pragma unroll
            for (int nt = 0; nt < 4; ++nt) {
                #pragma unroll
                for (int r = 0; r < 4; ++r)
                    p[nt][r] = fmaf(sA[nt][r], LOG2E, bb[nt][r]);
                mnt[nt] = fmaxf(fmaxf(p[nt][0], p[nt][1]), fmaxf(p[nt][2], p[nt][3]));
            }
            float mt = fmaxf(fmaxf(mnt[0], mnt[1]), fmaxf(mnt[2], mnt[3]));
            mt = fmaxf(mt, __shfl_xor(mt, 16));
            mt = fmaxf(mt, __shfl_xor(mt, 32));
            if (!__all(mt <= mA + 8.f)) {
                float mnew = fmaxf(mA, mt);
                float sc = __builtin_amdgcn_exp2f(mA - mnew);
                mA = mnew;
                lpA *= sc;
                #pragma unroll
                for (int dt = 0; dt < 4; ++dt) oA[dt] *= sc;
            }
            #pragma unroll
            for (int nt = 0; nt < 4; ++nt) {
                #pragma unroll
                for (int r = 0; r < 4; ++r) {
                    p[nt][r] = __builtin_amdgcn_exp2f(p[nt][r] - mA);
                    lpA[r] += p[nt][r];
                }
                bf16x4 pv;
                pv[0] = (__bf16)p[nt][0]; pv[1] = (__bf16)p[nt][1];
                pv[2] = (__bf16)p[nt][2]; pv[3] = (__bf16)p[nt][3];
                *(bf16x4*)(pbase + ((nt * 32 + lg * 8) ^ pxor)) = pv;
            }
            pfA0 = *(const bf16x8*)(pbase + ((lg * 16) ^ pxor));
            pfA1 = *(const bf16x8*)(pbase + ((64 + lg * 16) ^ pxor));
        }
        // ---- PV A (overlaps softmax B's VALU) ----
        __builtin_amdgcn_s_setprio(1);
        #pragma unroll
        for (int dt = 0; dt < 4; ++dt) {
            bf16x8 vf0 = *(const bf16x8*)&Vs[cur][dt * 16 + lr][c0];
            bf16x8 vf1 = *(const bf16x8*)&Vs[cur][dt * 16 + lr][c1];
            oA[dt] = __builtin_amdgcn_mfma_f32_16x16x32_bf16(vf0, pfA0, oA[dt], 0, 0, 0);
            oA[dt] = __builtin_amdgcn_mfma_f32_16x16x32_bf16(vf1, pfA1, oA[dt], 0, 0, 0);
        }
        __builtin_amdgcn_s_setprio(0);
        // ---- softmax B ----
        bf16x8 pfB0, pfB1;
        {
            float bb[4][4];
            if (far) {
                #pragma unroll
                for (int nt = 0; nt < 4; ++nt)
                    #pragma unroll
                    for (int r = 0; r < 4; ++r) bb[nt][r] = cb;
            } else {
                const int bi = kt + bbB;
                #pragma unroll
                for (int nt = 0; nt < 4; ++nt)
                    #pragma unroll
                    for (int r = 0; r < 4; ++r) bb[nt][r] = LbS[bi + nt * 16 + r];
            }
            float p[4][4]; float mnt[4];
            #pragma unroll
            for (int nt = 0; nt < 4; ++nt) {
                #pragma unroll
                for (int r = 0; r < 4; ++r)
                    p[nt][r] = fmaf(sB[nt][r], LOG2E, bb[nt][r]);
                mnt[nt] = fmaxf(fmaxf(p[nt][0], p[nt][1]), fmaxf(p[nt][2], p[nt][3]));
            }
            float mt = fmaxf(fmaxf(mnt[0], mnt[1]), fmaxf(mnt[2], mnt[3]));
            mt = fmaxf(mt, __shfl_xor(mt, 16));
            mt = fmaxf(mt, __shfl_xor(mt, 32));
            if (!__all(mt <= mB + 8.f)) {
                float mnew = fmaxf(mB, mt);
                float sc = __builtin_amdgcn_exp2f(mB - mnew);
                mB = mnew;
                lpB *= sc;
                #pragma unroll
                for (int dt = 0; dt < 4; ++dt) oB[dt] *= sc;
            }
            #pragma unroll
            for (int nt = 0; nt < 4; ++nt) {
                #pragma unroll
                for (int r = 0; r < 4; ++r) {
                    p[nt][r] = __builtin_amdgcn_exp2f(p[nt][r] - mB);
                    lpB[r] += p[nt][r];
                }
                bf16x4 pv;
                pv[0] = (__bf16)p[nt][0]; pv[1] = (__bf16)p[nt][1];
                pv[2] = (__bf16)p[nt][2]; pv[3] = (__bf16)p[nt][3];
                *(bf16x4*)(pbase + ((nt * 32 + lg * 8) ^ pxor)) = pv;
            }
            pfB0 = *(const bf16x8*)(pbase + ((lg * 16) ^ pxor));
            pfB1 = *(const bf16x8*)(pbase + ((64 + lg * 16) ^ pxor));
        }
        // ---- PV B ----
        __builtin_amdgcn_s_setprio(1);
        #pragma unroll
        for (int dt = 0; dt < 4; ++dt) {
            bf16x8 vf0 = *(const bf16x8*)&Vs[cur][dt * 16 + lr][c0];
            bf16x8 vf1 = *(const bf16x8*)&Vs[cur][dt * 16 + lr][c1];
            oB[dt] = __builtin_amdgcn_mfma_f32_16x16x32_bf16(vf0, pfB0, oB[dt], 0, 0, 0);
            oB[dt] = __builtin_amdgcn_mfma_f32_16x16x32_bf16(vf1, pfB1, oB[dt], 0, 0, 0);
        }
        __builtin_amdgcn_s_setprio(0);
        // tile end: next tile's K/V must have landed; raw barrier (no hidden drains)
        if (t < 31) {
            asm volatile("s_waitcnt vmcnt(0)" ::: "memory");
            __builtin_amdgcn_s_barrier();
            __builtin_amdgcn_sched_barrier(0);
        }
    }
    // final cross-lane l reduction
    float lA = (lpA[0] + lpA[1]) + (lpA[2] + lpA[3]);
    lA += __shfl_xor(lA, 16); lA += __shfl_xor(lA, 32);
    float lB = (lpB[0] + lpB[1]) + (lpB[2] + lpB[3]);
    lB += __shfl_xor(lB, 16); lB += __shfl_xor(lB, 32);
    // epilogue group A
    {
        float linv = 1.f / lA;
        char* pbase = (char*)&Ps[wid][lr][0];
        #pragma unroll
        for (int dt = 0; dt < 4; ++dt) {
            bf16x4 ov;
            ov[0] = (__bf16)(oA[dt][0] * linv); ov[1] = (__bf16)(oA[dt][1] * linv);
            ov[2] = (__bf16)(oA[dt][2] * linv); ov[3] = (__bf16)(oA[dt][3] * linv);
            *(bf16x4*)(pbase + ((dt * 32 + lg * 8) ^ pxor)) = ov;
        }
        int row = lane >> 2, seg = lane & 3;
        int rxor = (row & 7) << 4;
        char* rbase = (char*)&Ps[wid][row][0];
        uint4 v0 = *(uint4*)(rbase + ((seg * 32) ^ rxor));
        uint4 v1 = *(uint4*)(rbase + ((seg * 32 + 16) ^ rxor));
        ushort_t* dst = Out + (size_t)(b * S_ + q0w + row) * INNER_ + h * DKV_ + seg * 16;
        *(uint4*)&dst[0] = v0;
        *(uint4*)&dst[8] = v1;
    }
    // epilogue group B
    {
        float linv = 1.f / lB;
        char* pbase = (char*)&Ps[wid][lr][0];
        #pragma unroll
        for (int dt = 0; dt < 4; ++dt) {
            bf16x4 ov;
            ov[0] = (__bf16)(oB[dt][0] * linv); ov[1] = (__bf16)(oB[dt][1] * linv);
            ov[2] = (__bf16)(oB[dt][2] * linv); ov[3] = (__bf16)(oB[dt][3] * linv);
            *(bf16x4*)(pbase + ((dt * 32 + lg * 8) ^ pxor)) = ov;
        }
        int row = lane >> 2, seg = lane & 3;
        int rxor = (row & 7) << 4;
        char* rbase = (char*)&Ps[wid][row][0];
        uint4 v0 = *(uint4*)(rbase + ((seg * 32) ^ rxor));
        uint4 v1 = *(uint4*)(rbase + ((seg * 32 + 16) ^ rxor));
        ushort_t* dst = Out + (size_t)(b * S_ + q0w + 16 + row) * INNER_ + h * DKV_ + seg * 16;
        *(uint4*)&dst[0] = v0;
        *(uint4*)&dst[8] = v1;
    }
}

extern "C" void kernel_launch(void* const* d_in, const int* in_sizes, int n_in,
                              void* d_out, int out_size, void* d_ws, size_t ws_size,
                              hipStream_t stream) {
    const float* hs = (const float*)d_in[0];
    const float* wq = (const float*)d_in[1];
    const float* wk = (const float*)d_in[2];
    const float* wv = (const float*)d_in[3];
    const float* wo = (const float*)d_in[4];
    const float* rb = (const float*)d_in[5];

    char* ws = (char*)d_ws;
    unsigned short* Abf = (unsigned short*)(ws);                 // 8 MB  [4096][1024]
    unsigned short* Wqt = (unsigned short*)(ws + (8u  << 20));   // 2 MB  [1024][1024]
    unsigned short* Wkt = (unsigned short*)(ws + (10u << 20));
    unsigned short* Wvt = (unsigned short*)(ws + (12u << 20));
    unsigned short* Wot = (unsigned short*)(ws + (14u << 20));
    unsigned short* Qb  = (unsigned short*)(ws + (16u << 20));   // 8 MB  [b][h][s][64]
    unsigned short* Kb  = (unsigned short*)(ws + (24u << 20));   // 8 MB
    unsigned short* Vtb = (unsigned short*)(ws + (32u << 20));   // 8 MB  [b][h][64][s]
    unsigned short* AOb = (unsigned short*)(ws + (40u << 20));   // 8 MB  [4096][1024]
    float*          Btab = (float*)(ws + (48u << 20));           // 256 KB [16][4096]

    prep_kernel<<<5184, 256, 0, stream>>>(hs, wq, wk, wv, wo, rb,
                                          Abf, Wqt, Wkt, Wvt, Wot, Btab);

    gemm_qkv<<<768, 256, 0, stream>>>(Abf, Wqt, Wkt, Wvt, Qb, Kb, Vtb);

    flash_attn<<<512, 256, 0, stream>>>(Qb, Kb, Vtb, Btab, AOb);

    gemm_out<<<512, 256, 0, stream>>>(AOb, Wot, (float*)d_out);
}

// Round 8
// 130.246 us; speedup vs baseline: 1.8294x; 1.0283x over previous
//
#include <hip/hip_runtime.h>
#include <hip/hip_bf16.h>

#define B_ 2
#define S_ 2048
#define D_ 1024
#define H_ 16
#define DKV_ 64
#define INNER_ 1024
#define M_ (B_*S_)   // 4096

typedef unsigned short ushort_t;
typedef unsigned int u32;
typedef __bf16 bf16x8 __attribute__((ext_vector_type(8)));
typedef __bf16 bf16x4 __attribute__((ext_vector_type(4)));
typedef float f32x4 __attribute__((ext_vector_type(4)));

#define VMCNT0 asm volatile("s_waitcnt vmcnt(0)" ::: "memory")
#define LOG2E 1.4426950408889634f

__device__ __forceinline__ unsigned short f2bf(float f) {
    unsigned int u = __builtin_bit_cast(unsigned int, f);
    unsigned int r = (u + 0x7fffu + ((u >> 16) & 1u)) >> 16;
    return (unsigned short)r;
}

__device__ __forceinline__ void gload16(const ushort_t* g, ushort_t* l) {
    __builtin_amdgcn_global_load_lds(
        (const __attribute__((address_space(1))) u32*)g,
        (__attribute__((address_space(3))) u32*)l, 16, 0, 0);
}

// ---------------- fused prep: cvt(hidden) + transpose(weights) + bias table ----------------
__global__ __launch_bounds__(256) void prep_kernel(
        const float* __restrict__ hs,
        const float* __restrict__ s0, const float* __restrict__ s1,
        const float* __restrict__ s2, const float* __restrict__ s3,
        const float* __restrict__ rb,
        unsigned short* __restrict__ Abf,
        unsigned short* __restrict__ d0, unsigned short* __restrict__ d1,
        unsigned short* __restrict__ d2, unsigned short* __restrict__ d3,
        float* __restrict__ btab) {
    int bid = blockIdx.x, tid = threadIdx.x;
    if (bid < 4096) {
        int i = (bid * 256 + tid) * 4;
        float4 v = *(const float4*)&hs[i];
        ushort4 o;
        o.x = f2bf(v.x); o.y = f2bf(v.y); o.z = f2bf(v.z); o.w = f2bf(v.w);
        *(ushort4*)&Abf[i] = o;
    } else if (bid < 5120) {
        int t = bid - 4096;
        int z = t >> 8, rem = t & 255;
        int k0 = ((rem >> 4) & 15) * 64, n0 = (rem & 15) * 64;
        const float* srcs[4] = {s0, s1, s2, s3};
        unsigned short* dsts[4] = {d0, d1, d2, d3};
        const float* src = srcs[z];
        unsigned short* dst = dsts[z];
        __shared__ float tbuf[64][65];
        for (int i = tid; i < 4096; i += 256) {
            int r = i >> 6, c = i & 63;
            tbuf[r][c] = src[(k0 + r) * 1024 + n0 + c];
        }
        __syncthreads();
        for (int i = tid; i < 4096; i += 256) {
            int r = i >> 6, c = i & 63;
            dst[(n0 + r) * 1024 + k0 + c] = f2bf(tbuf[c][r]);
        }
    } else {
        #pragma unroll
        for (int j = 0; j < 4; ++j) {
            int idx = (bid - 5120) * 1024 + j * 256 + tid;
            int h = idx >> 12, pos = idx & 4095;
            int rel = pos - 2048;
            int bb = rel > 0 ? 16 : 0;
            int rp = rel < 0 ? -rel : rel;
            int bucket;
            if (rp < 8) bucket = bb + rp;
            else {
                int v = 8 + (int)(logf((float)rp * 0.125f) / 2.7725887f * 8.0f);
                bucket = bb + (v < 15 ? v : 15);
            }
            btab[idx] = rb[bucket * 16 + h] * LOG2E;
        }
    }
}

// ---------------- fused QKV GEMM: A[4096][1024] x {WQ,WK,WV}^T, 128x128 tile, BK=64 ----------------
__global__ __launch_bounds__(256) void gemm_qkv(const ushort_t* __restrict__ A,
        const ushort_t* __restrict__ WQ, const ushort_t* __restrict__ WK, const ushort_t* __restrict__ WV,
        ushort_t* __restrict__ Qb, ushort_t* __restrict__ Kb, ushort_t* __restrict__ Vtb) {
    __shared__ alignas(16) ushort_t As[128][64];
    __shared__ alignas(16) ushort_t Bs[128][64];
    int tid = threadIdx.x, wid = tid >> 6, lane = tid & 63;
    int linear = blockIdx.x;                    // 768 blocks
    int swz = (linear & 7) * 96 + (linear >> 3);
    int m0 = (swz / 24) * 128;
    int nblk = swz % 24;
    int sel = nblk >> 3;                        // 0=Q 1=K 2=V
    const ushort_t* Bt = sel == 0 ? WQ : (sel == 1 ? WK : WV);
    int n0 = (nblk & 7) * 128;
    int lr = lane & 15, lg = lane >> 4;
    int wm = (wid >> 1) * 64, wn = (wid & 1) * 64;
    int srow = tid >> 3, sp = tid & 7;
    int scol = (sp ^ (srow & 7)) * 8;
    int cR0 = (lg ^ (lr & 7)) * 8;
    int cR1 = ((4 + lg) ^ (lr & 7)) * 8;
    const ushort_t* Abase = A + (size_t)m0 * 1024 + scol;
    const ushort_t* Bbase = Bt + (size_t)n0 * 1024 + scol;
    f32x4 acc[4][4] = {};
    for (int kt = 0; kt < 1024; kt += 64) {
        #pragma unroll
        for (int j = 0; j < 4; ++j) {
            int row = j * 32 + srow;
            gload16(Abase + row * 1024 + kt, &As[0][0] + (j * 256 + tid) * 8);
            gload16(Bbase + row * 1024 + kt, &Bs[0][0] + (j * 256 + tid) * 8);
        }
        VMCNT0;
        __syncthreads();
        bf16x8 af[4][2], bfr[4][2];
        #pragma unroll
        for (int t = 0; t < 4; ++t) {
            af[t][0]  = *(const bf16x8*)&As[wm + t * 16 + lr][cR0];
            af[t][1]  = *(const bf16x8*)&As[wm + t * 16 + lr][cR1];
            bfr[t][0] = *(const bf16x8*)&Bs[wn + t * 16 + lr][cR0];
            bfr[t][1] = *(const bf16x8*)&Bs[wn + t * 16 + lr][cR1];
        }
        #pragma unroll
        for (int hh = 0; hh < 2; ++hh)
            #pragma unroll
            for (int i2 = 0; i2 < 4; ++i2)
                #pragma unroll
                for (int j2 = 0; j2 < 4; ++j2)
                    acc[i2][j2] = __builtin_amdgcn_mfma_f32_16x16x32_bf16(af[i2][hh], bfr[j2][hh], acc[i2][j2], 0, 0, 0);
        __syncthreads();
    }
    #pragma unroll
    for (int i2 = 0; i2 < 4; ++i2)
        #pragma unroll
        for (int j2 = 0; j2 < 4; ++j2) {
            int col = n0 + wn + j2 * 16 + lr;
            int hh = col >> 6, d = col & 63;
            if (sel < 2) {
                ushort_t* dst = sel == 0 ? Qb : Kb;
                #pragma unroll
                for (int r = 0; r < 4; ++r) {
                    int row = m0 + wm + i2 * 16 + lg * 4 + r;
                    int b = row >> 11, s = row & 2047;
                    dst[(((size_t)(b * H_ + hh) * S_ + s)) * DKV_ + d] = f2bf(acc[i2][j2][r]);
                }
            } else {
                int row0 = m0 + wm + i2 * 16 + lg * 4;
                int b = row0 >> 11, s0 = row0 & 2047;
                ushort4 sv;
                sv.x = f2bf(acc[i2][j2][0]); sv.y = f2bf(acc[i2][j2][1]);
                sv.z = f2bf(acc[i2][j2][2]); sv.w = f2bf(acc[i2][j2][3]);
                *(ushort4*)&Vtb[((size_t)(b * H_ + hh) * DKV_ + d) * S_ + s0] = sv;
            }
        }
}

// ---------------- output projection GEMM: 64x128 tile, BK=64, fp32 out ----------------
__global__ __launch_bounds__(256) void gemm_out(const ushort_t* __restrict__ A,
                                                const ushort_t* __restrict__ Bt,
                                                float* __restrict__ C) {
    __shared__ alignas(16) ushort_t As[64][64];
    __shared__ alignas(16) ushort_t Bs[128][64];
    int tid = threadIdx.x, wid = tid >> 6, lane = tid & 63;
    int linear = blockIdx.x;                    // 512 blocks
    int swz = (linear & 7) * 64 + (linear >> 3);
    int m0 = (swz >> 3) * 64, n0 = (swz & 7) * 128;
    int lr = lane & 15, lg = lane >> 4;
    int wn = wid * 32;
    int srow = tid >> 3, sp = tid & 7;
    int scol = (sp ^ (srow & 7)) * 8;
    int cR0 = (lg ^ (lr & 7)) * 8;
    int cR1 = ((4 + lg) ^ (lr & 7)) * 8;
    const ushort_t* Abase = A + (size_t)m0 * 1024 + scol;
    const ushort_t* Bbase = Bt + (size_t)n0 * 1024 + scol;
    f32x4 acc[4][2] = {};
    for (int kt = 0; kt < 1024; kt += 64) {
        #pragma unroll
        for (int j = 0; j < 2; ++j) {
            int row = j * 32 + srow;
            gload16(Abase + row * 1024 + kt, &As[0][0] + (j * 256 + tid) * 8);
        }
        #pragma unroll
        for (int j = 0; j < 4; ++j) {
            int row = j * 32 + srow;
            gload16(Bbase + row * 1024 + kt, &Bs[0][0] + (j * 256 + tid) * 8);
        }
        VMCNT0;
        __syncthreads();
        bf16x8 af[4][2], bfr[2][2];
        #pragma unroll
        for (int t = 0; t < 4; ++t) {
            af[t][0] = *(const bf16x8*)&As[t * 16 + lr][cR0];
            af[t][1] = *(const bf16x8*)&As[t * 16 + lr][cR1];
        }
        #pragma unroll
        for (int j = 0; j < 2; ++j) {
            bfr[j][0] = *(const bf16x8*)&Bs[wn + j * 16 + lr][cR0];
            bfr[j][1] = *(const bf16x8*)&Bs[wn + j * 16 + lr][cR1];
        }
        #pragma unroll
        for (int hh = 0; hh < 2; ++hh)
            #pragma unroll
            for (int i2 = 0; i2 < 4; ++i2)
                #pragma unroll
                for (int j2 = 0; j2 < 2; ++j2)
                    acc[i2][j2] = __builtin_amdgcn_mfma_f32_16x16x32_bf16(af[i2][hh], bfr[j2][hh], acc[i2][j2], 0, 0, 0);
        __syncthreads();
    }
    #pragma unroll
    for (int i2 = 0; i2 < 4; ++i2)
        #pragma unroll
        for (int j2 = 0; j2 < 2; ++j2)
            #pragma unroll
            for (int r = 0; r < 4; ++r)
                C[(size_t)(m0 + i2 * 16 + lg * 4 + r) * 1024 + n0 + wn + j2 * 16 + lr] = acc[i2][j2][r];
}

// ---------------- flash attention v5: cross-tile QK pipeline, K[2]+V[3] LDS, counted vmcnt ----------------
__global__ __launch_bounds__(256, 2) void flash_attn(const ushort_t* __restrict__ Q,
                                                     const ushort_t* __restrict__ Kg,
                                                     const ushort_t* __restrict__ Vt,
                                                     const float* __restrict__ bias_tab,
                                                     ushort_t* __restrict__ Out) {
    __shared__ alignas(16) ushort_t Ks[2][64][64];
    __shared__ alignas(16) ushort_t Vs[3][64][64];
    __shared__ alignas(16) ushort_t Ps[4][16][64];
    __shared__ float LbS[2176];
    int tid = threadIdx.x, wid = tid >> 6, lane = tid & 63;
    int linear = blockIdx.x;                 // 512 blocks
    int swz = (linear & 7) * 64 + (linear >> 3);
    int bh = swz >> 4, qblk = swz & 15;
    int h = bh & 15, b = bh >> 4;
    int q0b = qblk * 128;
    int q0w = q0b + wid * 32;                // this wave: q0w..q0w+31 (2 groups of 16)
    int lr = lane & 15, lg = lane >> 4;

    // bias slice + saturated constants
    {
        const float* bsrc = bias_tab + h * 4096 + 2048 - q0b - 127;
        for (int i = tid; i < 2175; i += 256) LbS[i] = bsrc[i];
    }
    float cpos = bias_tab[h * 4096 + 4095];   // rel >= 128 (bucket 31)
    float cneg = bias_tab[h * 4096 + 0];      // rel <= -128 (bucket 15)

    // Q fragments, both groups
    const ushort_t* Qbase = Q + ((size_t)bh * S_ + q0w) * DKV_;
    bf16x8 qA0 = *(const bf16x8*)&Qbase[lr * DKV_ + lg * 8];
    bf16x8 qA1 = *(const bf16x8*)&Qbase[lr * DKV_ + 32 + lg * 8];
    bf16x8 qB0 = *(const bf16x8*)&Qbase[(16 + lr) * DKV_ + lg * 8];
    bf16x8 qB1 = *(const bf16x8*)&Qbase[(16 + lr) * DKV_ + 32 + lg * 8];

    // staging geometry (pre-swizzled source)
    int srow = tid >> 3, sp = tid & 7;
    int kc = (sp ^ (srow & 7)) * 8;
    const ushort_t* Ksrc = Kg + (size_t)bh * S_ * DKV_ + kc;
    const ushort_t* Vsrc = Vt + (size_t)bh * DKV_ * S_ + kc;
    // swizzled fragment-read columns
    int c0 = (lg ^ (lr & 7)) * 8;
    int c1 = ((4 + lg) ^ (lr & 7)) * 8;
    int pxor = (lr & 7) << 4;

    f32x4 oA[4] = {}, oB[4] = {};
    f32x4 lpA = {}, lpB = {};
    float mA = -INFINITY, mB = -INFINITY;
    const int bbA = 127 - wid * 32 + 4 * lg - lr;
    const int bbB = bbA - 16;

    auto stageK = [&](int bi, int kt) {
        ushort_t* kb = &Ks[bi][0][0];
        gload16(Ksrc + (size_t)(kt + srow) * 64,      kb + tid * 8);
        gload16(Ksrc + (size_t)(kt + 32 + srow) * 64, kb + 2048 + tid * 8);
    };
    auto stageV = [&](int bi, int kt) {
        ushort_t* vb = &Vs[bi][0][0];
        gload16(Vsrc + (size_t)srow * S_ + kt,        vb + tid * 8);
        gload16(Vsrc + (size_t)(32 + srow) * S_ + kt, vb + 2048 + tid * 8);
    };
    auto qk = [&](int buf, f32x4* sA, f32x4* sB) {
        __builtin_amdgcn_s_setprio(1);
        #pragma unroll
        for (int nt = 0; nt < 4; ++nt) {
            bf16x8 kf0 = *(const bf16x8*)&Ks[buf][nt * 16 + lr][c0];
            bf16x8 kf1 = *(const bf16x8*)&Ks[buf][nt * 16 + lr][c1];
            sA[nt] = __builtin_amdgcn_mfma_f32_16x16x32_bf16(kf0, qA0, sA[nt], 0, 0, 0);
            sA[nt] = __builtin_amdgcn_mfma_f32_16x16x32_bf16(kf1, qA1, sA[nt], 0, 0, 0);
            sB[nt] = __builtin_amdgcn_mfma_f32_16x16x32_bf16(kf0, qB0, sB[nt], 0, 0, 0);
            sB[nt] = __builtin_amdgcn_mfma_f32_16x16x32_bf16(kf1, qB1, sB[nt], 0, 0, 0);
        }
        __builtin_amdgcn_s_setprio(0);
    };
    // softmax + PV for one q-group; s = scores of tile t, vbuf = V(t)
    auto smpv = [&](f32x4 (&s)[4], float& m, f32x4& lp, f32x4 (&o)[4],
                    int bi, bool far, float cb, const ushort_t* vbuf) {
        float p[4][4];
        if (far) {
            #pragma unroll
            for (int nt = 0; nt < 4; ++nt)
                #pragma unroll
                for (int r = 0; r < 4; ++r)
                    p[nt][r] = fmaf(s[nt][r], LOG2E, cb);
        } else {
            #pragma unroll
            for (int nt = 0; nt < 4; ++nt)
                #pragma unroll
                for (int r = 0; r < 4; ++r)
                    p[nt][r] = fmaf(s[nt][r], LOG2E, LbS[bi + nt * 16 + r]);
        }
        float mnt[4];
        #pragma unroll
        for (int nt = 0; nt < 4; ++nt)
            mnt[nt] = fmaxf(fmaxf(p[nt][0], p[nt][1]), fmaxf(p[nt][2], p[nt][3]));
        float mt = fmaxf(fmaxf(mnt[0], mnt[1]), fmaxf(mnt[2], mnt[3]));
        mt = fmaxf(mt, __shfl_xor(mt, 16));
        mt = fmaxf(mt, __shfl_xor(mt, 32));
        if (!__all(mt <= m + 8.f)) {
            float mnew = fmaxf(m, mt);
            float sc = __builtin_amdgcn_exp2f(m - mnew);
            m = mnew;
            lp *= sc;
            #pragma unroll
            for (int dt = 0; dt < 4; ++dt) o[dt] *= sc;
        }
        char* pbase = (char*)&Ps[wid][lr][0];
        #pragma unroll
        for (int nt = 0; nt < 4; ++nt) {
            #pragma unroll
            for (int r = 0; r < 4; ++r) {
                p[nt][r] = __builtin_amdgcn_exp2f(p[nt][r] - m);
                lp[r] += p[nt][r];
            }
            bf16x4 pv;
            pv[0] = (__bf16)p[nt][0]; pv[1] = (__bf16)p[nt][1];
            pv[2] = (__bf16)p[nt][2]; pv[3] = (__bf16)p[nt][3];
            *(bf16x4*)(pbase + ((nt * 32 + lg * 8) ^ pxor)) = pv;
        }
        bf16x8 pf0 = *(const bf16x8*)(pbase + ((lg * 16) ^ pxor));
        bf16x8 pf1 = *(const bf16x8*)(pbase + ((64 + lg * 16) ^ pxor));
        __builtin_amdgcn_s_setprio(1);
        #pragma unroll
        for (int dt = 0; dt < 4; ++dt) {
            bf16x8 vf0 = *(const bf16x8*)&vbuf[(dt * 16 + lr) * 64 + c0];
            bf16x8 vf1 = *(const bf16x8*)&vbuf[(dt * 16 + lr) * 64 + c1];
            o[dt] = __builtin_amdgcn_mfma_f32_16x16x32_bf16(vf0, pf0, o[dt], 0, 0, 0);
            o[dt] = __builtin_amdgcn_mfma_f32_16x16x32_bf16(vf1, pf1, o[dt], 0, 0, 0);
        }
        __builtin_amdgcn_s_setprio(0);
    };

    // prologue: K(0),V(0),K(1),V(1)
    stageK(0, 0); stageV(0, 0);
    stageK(1, 64); stageV(1, 64);
    asm volatile("s_waitcnt vmcnt(0) lgkmcnt(0)" ::: "memory");
    __builtin_amdgcn_s_barrier();
    __builtin_amdgcn_sched_barrier(0);

    f32x4 sCA[4] = {}, sCB[4] = {};
    qk(0, sCA, sCB);                          // QK(0)
    __builtin_amdgcn_s_barrier();             // all waves done reading Ks[0] before iter-0 overwrites it
    __builtin_amdgcn_sched_barrier(0);

    int vuse = 0, vstg = 2;
    for (int t = 0; t < 32; ++t) {
        const int kt = t * 64;
        if (t < 30) {                         // stage tile t+2 (K -> Ks[t&1], V -> Vs[(t+2)%3])
            stageK(t & 1, kt + 128);
            stageV(vstg, kt + 128);
        }
        __builtin_amdgcn_sched_barrier(0);    // pin load issue before compute
        // QK(t+1): independent of softmax(t) -> MFMA/VALU overlap
        f32x4 sNA[4] = {}, sNB[4] = {};
        if (t < 31) qk((t + 1) & 1, sNA, sNB);
        // softmax(t) + PV(t)
        const bool far = (kt >= q0b + 256) || (kt + 64 <= q0b - 128);
        const float cb = (kt > q0b) ? cpos : cneg;
        const ushort_t* vbuf = &Vs[vuse][0][0];
        smpv(sCA, mA, lpA, oA, kt + bbA, far, cb, vbuf);
        smpv(sCB, mB, lpB, oB, kt + bbB, far, cb, vbuf);
        // hand off scores
        #pragma unroll
        for (int nt = 0; nt < 4; ++nt) { sCA[nt] = sNA[nt]; sCB[nt] = sNB[nt]; }
        // end-of-iter: K(t+2) + V(t+1) must be landed; V(t+2) may stay in flight
        if (t < 31) {
            if (t < 30) { asm volatile("s_waitcnt vmcnt(2)" ::: "memory"); }
            else        { asm volatile("s_waitcnt vmcnt(0)" ::: "memory"); }
            __builtin_amdgcn_s_barrier();
            __builtin_amdgcn_sched_barrier(0);
        }
        ++vuse; if (vuse >= 3) vuse = 0;
        ++vstg; if (vstg >= 3) vstg = 0;
    }

    // final cross-lane l reduction
    float lA = (lpA[0] + lpA[1]) + (lpA[2] + lpA[3]);
    lA += __shfl_xor(lA, 16); lA += __shfl_xor(lA, 32);
    float lB = (lpB[0] + lpB[1]) + (lpB[2] + lpB[3]);
    lB += __shfl_xor(lB, 16); lB += __shfl_xor(lB, 32);
    // epilogue group A
    {
        float linv = 1.f / lA;
        char* pbase = (char*)&Ps[wid][lr][0];
        #pragma unroll
        for (int dt = 0; dt < 4; ++dt) {
            bf16x4 ov;
            ov[0] = (__bf16)(oA[dt][0] * linv); ov[1] = (__bf16)(oA[dt][1] * linv);
            ov[2] = (__bf16)(oA[dt][2] * linv); ov[3] = (__bf16)(oA[dt][3] * linv);
            *(bf16x4*)(pbase + ((dt * 32 + lg * 8) ^ pxor)) = ov;
        }
        int row = lane >> 2, seg = lane & 3;
        int rxor = (row & 7) << 4;
        char* rbase = (char*)&Ps[wid][row][0];
        uint4 v0 = *(uint4*)(rbase + ((seg * 32) ^ rxor));
        uint4 v1 = *(uint4*)(rbase + ((seg * 32 + 16) ^ rxor));
        ushort_t* dst = Out + (size_t)(b * S_ + q0w + row) * INNER_ + h * DKV_ + seg * 16;
        *(uint4*)&dst[0] = v0;
        *(uint4*)&dst[8] = v1;
    }
    // epilogue group B
    {
        float linv = 1.f / lB;
        char* pbase = (char*)&Ps[wid][lr][0];
        #pragma unroll
        for (int dt = 0; dt < 4; ++dt) {
            bf16x4 ov;
            ov[0] = (__bf16)(oB[dt][0] * linv); ov[1] = (__bf16)(oB[dt][1] * linv);
            ov[2] = (__bf16)(oB[dt][2] * linv); ov[3] = (__bf16)(oB[dt][3] * linv);
            *(bf16x4*)(pbase + ((dt * 32 + lg * 8) ^ pxor)) = ov;
        }
        int row = lane >> 2, seg = lane & 3;
        int rxor = (row & 7) << 4;
        char* rbase = (char*)&Ps[wid][row][0];
        uint4 v0 = *(uint4*)(rbase + ((seg * 32) ^ rxor));
        uint4 v1 = *(uint4*)(rbase + ((seg * 32 + 16) ^ rxor));
        ushort_t* dst = Out + (size_t)(b * S_ + q0w + 16 + row) * INNER_ + h * DKV_ + seg * 16;
        *(uint4*)&dst[0] = v0;
        *(uint4*)&dst[8] = v1;
    }
}

extern "C" void kernel_launch(void* const* d_in, const int* in_sizes, int n_in,
                              void* d_out, int out_size, void* d_ws, size_t ws_size,
                              hipStream_t stream) {
    const float* hs = (const float*)d_in[0];
    const float* wq = (const float*)d_in[1];
    const float* wk = (const float*)d_in[2];
    const float* wv = (const float*)d_in[3];
    const float* wo = (const float*)d_in[4];
    const float* rb = (const float*)d_in[5];

    char* ws = (char*)d_ws;
    unsigned short* Abf = (unsigned short*)(ws);                 // 8 MB  [4096][1024]
    unsigned short* Wqt = (unsigned short*)(ws + (8u  << 20));   // 2 MB  [1024][1024]
    unsigned short* Wkt = (unsigned short*)(ws + (10u << 20));
    unsigned short* Wvt = (unsigned short*)(ws + (12u << 20));
    unsigned short* Wot = (unsigned short*)(ws + (14u << 20));
    unsigned short* Qb  = (unsigned short*)(ws + (16u << 20));   // 8 MB  [b][h][s][64]
    unsigned short* Kb  = (unsigned short*)(ws + (24u << 20));   // 8 MB
    unsigned short* Vtb = (unsigned short*)(ws + (32u << 20));   // 8 MB  [b][h][64][s]
    unsigned short* AOb = (unsigned short*)(ws + (40u << 20));   // 8 MB  [4096][1024]
    float*          Btab = (float*)(ws + (48u << 20));           // 256 KB [16][4096]

    prep_kernel<<<5184, 256, 0, stream>>>(hs, wq, wk, wv, wo, rb,
                                          Abf, Wqt, Wkt, Wvt, Wot, Btab);

    gemm_qkv<<<768, 256, 0, stream>>>(Abf, Wqt, Wkt, Wvt, Qb, Kb, Vtb);

    flash_attn<<<512, 256, 0, stream>>>(Qb, Kb, Vtb, Btab, AOb);

    gemm_out<<<512, 256, 0, stream>>>(AOb, Wot, (float*)d_out);
}

// Round 9
// 130.045 us; speedup vs baseline: 1.8322x; 1.0015x over previous
//
#include <hip/hip_runtime.h>
#include <hip/hip_bf16.h>

#define B_ 2
#define S_ 2048
#define D_ 1024
#define H_ 16
#define DKV_ 64
#define INNER_ 1024
#define M_ (B_*S_)   // 4096

typedef unsigned short ushort_t;
typedef unsigned int u32;
typedef __bf16 bf16x8 __attribute__((ext_vector_type(8)));
typedef __bf16 bf16x4 __attribute__((ext_vector_type(4)));
typedef float f32x4 __attribute__((ext_vector_type(4)));

#define VMCNT0 asm volatile("s_waitcnt vmcnt(0)" ::: "memory")
#define LOG2E 1.4426950408889634f

__device__ __forceinline__ unsigned short f2bf(float f) {
    unsigned int u = __builtin_bit_cast(unsigned int, f);
    unsigned int r = (u + 0x7fffu + ((u >> 16) & 1u)) >> 16;
    return (unsigned short)r;
}

__device__ __forceinline__ void gload16(const ushort_t* g, ushort_t* l) {
    __builtin_amdgcn_global_load_lds(
        (const __attribute__((address_space(1))) u32*)g,
        (__attribute__((address_space(3))) u32*)l, 16, 0, 0);
}

// ---------------- fused prep: cvt(hidden) + transpose(weights) + bias table ----------------
__global__ __launch_bounds__(256) void prep_kernel(
        const float* __restrict__ hs,
        const float* __restrict__ s0, const float* __restrict__ s1,
        const float* __restrict__ s2, const float* __restrict__ s3,
        const float* __restrict__ rb,
        unsigned short* __restrict__ Abf,
        unsigned short* __restrict__ d0, unsigned short* __restrict__ d1,
        unsigned short* __restrict__ d2, unsigned short* __restrict__ d3,
        float* __restrict__ btab) {
    int bid = blockIdx.x, tid = threadIdx.x;
    if (bid < 4096) {
        int i = (bid * 256 + tid) * 4;
        float4 v = *(const float4*)&hs[i];
        ushort4 o;
        o.x = f2bf(v.x); o.y = f2bf(v.y); o.z = f2bf(v.z); o.w = f2bf(v.w);
        *(ushort4*)&Abf[i] = o;
    } else if (bid < 5120) {
        int t = bid - 4096;
        int z = t >> 8, rem = t & 255;
        int k0 = ((rem >> 4) & 15) * 64, n0 = (rem & 15) * 64;
        const float* srcs[4] = {s0, s1, s2, s3};
        unsigned short* dsts[4] = {d0, d1, d2, d3};
        const float* src = srcs[z];
        unsigned short* dst = dsts[z];
        __shared__ float tbuf[64][65];
        for (int i = tid; i < 4096; i += 256) {
            int r = i >> 6, c = i & 63;
            tbuf[r][c] = src[(k0 + r) * 1024 + n0 + c];
        }
        __syncthreads();
        for (int i = tid; i < 4096; i += 256) {
            int r = i >> 6, c = i & 63;
            dst[(n0 + r) * 1024 + k0 + c] = f2bf(tbuf[c][r]);
        }
    } else {
        #pragma unroll
        for (int j = 0; j < 4; ++j) {
            int idx = (bid - 5120) * 1024 + j * 256 + tid;
            int h = idx >> 12, pos = idx & 4095;
            int rel = pos - 2048;
            int bb = rel > 0 ? 16 : 0;
            int rp = rel < 0 ? -rel : rel;
            int bucket;
            if (rp < 8) bucket = bb + rp;
            else {
                int v = 8 + (int)(logf((float)rp * 0.125f) / 2.7725887f * 8.0f);
                bucket = bb + (v < 15 ? v : 15);
            }
            btab[idx] = rb[bucket * 16 + h] * LOG2E;
        }
    }
}

// ---------------- fused QKV GEMM: A[4096][1024] x {WQ,WK,WV}^T, 128x128 tile, BK=64 ----------------
__global__ __launch_bounds__(256) void gemm_qkv(const ushort_t* __restrict__ A,
        const ushort_t* __restrict__ WQ, const ushort_t* __restrict__ WK, const ushort_t* __restrict__ WV,
        ushort_t* __restrict__ Qb, ushort_t* __restrict__ Kb, ushort_t* __restrict__ Vtb) {
    __shared__ alignas(16) ushort_t As[128][64];
    __shared__ alignas(16) ushort_t Bs[128][64];
    int tid = threadIdx.x, wid = tid >> 6, lane = tid & 63;
    int linear = blockIdx.x;                    // 768 blocks
    int swz = (linear & 7) * 96 + (linear >> 3);
    int m0 = (swz / 24) * 128;
    int nblk = swz % 24;
    int sel = nblk >> 3;                        // 0=Q 1=K 2=V
    const ushort_t* Bt = sel == 0 ? WQ : (sel == 1 ? WK : WV);
    int n0 = (nblk & 7) * 128;
    int lr = lane & 15, lg = lane >> 4;
    int wm = (wid >> 1) * 64, wn = (wid & 1) * 64;
    int srow = tid >> 3, sp = tid & 7;
    int scol = (sp ^ (srow & 7)) * 8;
    int cR0 = (lg ^ (lr & 7)) * 8;
    int cR1 = ((4 + lg) ^ (lr & 7)) * 8;
    const ushort_t* Abase = A + (size_t)m0 * 1024 + scol;
    const ushort_t* Bbase = Bt + (size_t)n0 * 1024 + scol;
    f32x4 acc[4][4] = {};
    for (int kt = 0; kt < 1024; kt += 64) {
        #pragma unroll
        for (int j = 0; j < 4; ++j) {
            int row = j * 32 + srow;
            gload16(Abase + row * 1024 + kt, &As[0][0] + (j * 256 + tid) * 8);
            gload16(Bbase + row * 1024 + kt, &Bs[0][0] + (j * 256 + tid) * 8);
        }
        VMCNT0;
        __syncthreads();
        bf16x8 af[4][2], bfr[4][2];
        #pragma unroll
        for (int t = 0; t < 4; ++t) {
            af[t][0]  = *(const bf16x8*)&As[wm + t * 16 + lr][cR0];
            af[t][1]  = *(const bf16x8*)&As[wm + t * 16 + lr][cR1];
            bfr[t][0] = *(const bf16x8*)&Bs[wn + t * 16 + lr][cR0];
            bfr[t][1] = *(const bf16x8*)&Bs[wn + t * 16 + lr][cR1];
        }
        #pragma unroll
        for (int hh = 0; hh < 2; ++hh)
            #pragma unroll
            for (int i2 = 0; i2 < 4; ++i2)
                #pragma unroll
                for (int j2 = 0; j2 < 4; ++j2)
                    acc[i2][j2] = __builtin_amdgcn_mfma_f32_16x16x32_bf16(af[i2][hh], bfr[j2][hh], acc[i2][j2], 0, 0, 0);
        __syncthreads();
    }
    #pragma unroll
    for (int i2 = 0; i2 < 4; ++i2)
        #pragma unroll
        for (int j2 = 0; j2 < 4; ++j2) {
            int col = n0 + wn + j2 * 16 + lr;
            int hh = col >> 6, d = col & 63;
            if (sel < 2) {
                ushort_t* dst = sel == 0 ? Qb : Kb;
                #pragma unroll
                for (int r = 0; r < 4; ++r) {
                    int row = m0 + wm + i2 * 16 + lg * 4 + r;
                    int b = row >> 11, s = row & 2047;
                    dst[(((size_t)(b * H_ + hh) * S_ + s)) * DKV_ + d] = f2bf(acc[i2][j2][r]);
                }
            } else {
                int row0 = m0 + wm + i2 * 16 + lg * 4;
                int b = row0 >> 11, s0 = row0 & 2047;
                ushort4 sv;
                sv.x = f2bf(acc[i2][j2][0]); sv.y = f2bf(acc[i2][j2][1]);
                sv.z = f2bf(acc[i2][j2][2]); sv.w = f2bf(acc[i2][j2][3]);
                *(ushort4*)&Vtb[((size_t)(b * H_ + hh) * DKV_ + d) * S_ + s0] = sv;
            }
        }
}

// ---------------- output projection GEMM: 64x128 tile, BK=64, fp32 out ----------------
__global__ __launch_bounds__(256) void gemm_out(const ushort_t* __restrict__ A,
                                                const ushort_t* __restrict__ Bt,
                                                float* __restrict__ C) {
    __shared__ alignas(16) ushort_t As[64][64];
    __shared__ alignas(16) ushort_t Bs[128][64];
    int tid = threadIdx.x, wid = tid >> 6, lane = tid & 63;
    int linear = blockIdx.x;                    // 512 blocks
    int swz = (linear & 7) * 64 + (linear >> 3);
    int m0 = (swz >> 3) * 64, n0 = (swz & 7) * 128;
    int lr = lane & 15, lg = lane >> 4;
    int wn = wid * 32;
    int srow = tid >> 3, sp = tid & 7;
    int scol = (sp ^ (srow & 7)) * 8;
    int cR0 = (lg ^ (lr & 7)) * 8;
    int cR1 = ((4 + lg) ^ (lr & 7)) * 8;
    const ushort_t* Abase = A + (size_t)m0 * 1024 + scol;
    const ushort_t* Bbase = Bt + (size_t)n0 * 1024 + scol;
    f32x4 acc[4][2] = {};
    for (int kt = 0; kt < 1024; kt += 64) {
        #pragma unroll
        for (int j = 0; j < 2; ++j) {
            int row = j * 32 + srow;
            gload16(Abase + row * 1024 + kt, &As[0][0] + (j * 256 + tid) * 8);
        }
        #pragma unroll
        for (int j = 0; j < 4; ++j) {
            int row = j * 32 + srow;
            gload16(Bbase + row * 1024 + kt, &Bs[0][0] + (j * 256 + tid) * 8);
        }
        VMCNT0;
        __syncthreads();
        bf16x8 af[4][2], bfr[2][2];
        #pragma unroll
        for (int t = 0; t < 4; ++t) {
            af[t][0] = *(const bf16x8*)&As[t * 16 + lr][cR0];
            af[t][1] = *(const bf16x8*)&As[t * 16 + lr][cR1];
        }
        #pragma unroll
        for (int j = 0; j < 2; ++j) {
            bfr[j][0] = *(const bf16x8*)&Bs[wn + j * 16 + lr][cR0];
            bfr[j][1] = *(const bf16x8*)&Bs[wn + j * 16 + lr][cR1];
        }
        #pragma unroll
        for (int hh = 0; hh < 2; ++hh)
            #pragma unroll
            for (int i2 = 0; i2 < 4; ++i2)
                #pragma unroll
                for (int j2 = 0; j2 < 2; ++j2)
                    acc[i2][j2] = __builtin_amdgcn_mfma_f32_16x16x32_bf16(af[i2][hh], bfr[j2][hh], acc[i2][j2], 0, 0, 0);
        __syncthreads();
    }
    #pragma unroll
    for (int i2 = 0; i2 < 4; ++i2)
        #pragma unroll
        for (int j2 = 0; j2 < 2; ++j2)
            #pragma unroll
            for (int r = 0; r < 4; ++r)
                C[(size_t)(m0 + i2 * 16 + lg * 4 + r) * 1024 + n0 + wn + j2 * 16 + lr] = acc[i2][j2][r];
}

// ---------------- flash attention v6: fixed-ref softmax (m=0), QK pipeline, V in regs ----------------
__global__ __launch_bounds__(256, 2) void flash_attn(const ushort_t* __restrict__ Q,
                                                     const ushort_t* __restrict__ Kg,
                                                     const ushort_t* __restrict__ Vt,
                                                     const float* __restrict__ bias_tab,
                                                     ushort_t* __restrict__ Out) {
    __shared__ alignas(16) ushort_t Ks[2][64][64];
    __shared__ alignas(16) ushort_t Ps[4][16][64];
    __shared__ float LbS[2176];
    int tid = threadIdx.x, wid = tid >> 6, lane = tid & 63;
    int linear = blockIdx.x;                 // 512 blocks
    int swz = (linear & 7) * 64 + (linear >> 3);
    int bh = swz >> 4, qblk = swz & 15;
    int h = bh & 15, b = bh >> 4;
    int q0b = qblk * 128;
    int q0w = q0b + wid * 32;                // this wave: q0w..q0w+31 (2 groups of 16)
    int lr = lane & 15, lg = lane >> 4;

    // bias slice + saturated constants (all pre-scaled by log2e)
    {
        const float* bsrc = bias_tab + h * 4096 + 2048 - q0b - 127;
        for (int i = tid; i < 2175; i += 256) LbS[i] = bsrc[i];
    }
    float cpos = bias_tab[h * 4096 + 4095];   // rel >= 128 (bucket 31)
    float cneg = bias_tab[h * 4096 + 0];      // rel <= -128 (bucket 15)

    // Q fragments, both groups
    const ushort_t* Qbase = Q + ((size_t)bh * S_ + q0w) * DKV_;
    bf16x8 qA0 = *(const bf16x8*)&Qbase[lr * DKV_ + lg * 8];
    bf16x8 qA1 = *(const bf16x8*)&Qbase[lr * DKV_ + 32 + lg * 8];
    bf16x8 qB0 = *(const bf16x8*)&Qbase[(16 + lr) * DKV_ + lg * 8];
    bf16x8 qB1 = *(const bf16x8*)&Qbase[(16 + lr) * DKV_ + 32 + lg * 8];

    // K staging geometry (pre-swizzled source)
    int srow = tid >> 3, sp = tid & 7;
    int kc = (sp ^ (srow & 7)) * 8;
    const ushort_t* Ksrc = Kg + (size_t)bh * S_ * DKV_ + kc;
    // V direct fragment base: row = bh*64 + dt*16 + lr, cols kt + lg*8 (+32)
    const ushort_t* Vfrag = Vt + ((size_t)bh * DKV_ + lr) * S_ + lg * 8;
    // swizzled K fragment-read columns
    int c0 = (lg ^ (lr & 7)) * 8;
    int c1 = ((4 + lg) ^ (lr & 7)) * 8;
    int pxor = (lr & 7) << 4;

    f32x4 oA[4] = {}, oB[4] = {};
    f32x4 lpA = {}, lpB = {};
    const int bbA = 127 - wid * 32 + 4 * lg - lr;
    const int bbB = bbA - 16;

    auto stageK = [&](int bi, int kt) {
        ushort_t* kb = &Ks[bi][0][0];
        gload16(Ksrc + (size_t)(kt + srow) * 64,      kb + tid * 8);
        gload16(Ksrc + (size_t)(kt + 32 + srow) * 64, kb + 2048 + tid * 8);
    };
    auto loadV = [&](int kt, bf16x8 (&v)[4][2]) {
        #pragma unroll
        for (int dt = 0; dt < 4; ++dt) {
            const ushort_t* vp = Vfrag + (size_t)dt * 16 * S_ + kt;
            v[dt][0] = *(const bf16x8*)vp;
            v[dt][1] = *(const bf16x8*)(vp + 32);
        }
    };
    auto qk = [&](int buf, f32x4* sA, f32x4* sB) {
        __builtin_amdgcn_s_setprio(1);
        #pragma unroll
        for (int nt = 0; nt < 4; ++nt) {
            bf16x8 kf0 = *(const bf16x8*)&Ks[buf][nt * 16 + lr][c0];
            bf16x8 kf1 = *(const bf16x8*)&Ks[buf][nt * 16 + lr][c1];
            sA[nt] = __builtin_amdgcn_mfma_f32_16x16x32_bf16(kf0, qA0, sA[nt], 0, 0, 0);
            sA[nt] = __builtin_amdgcn_mfma_f32_16x16x32_bf16(kf1, qA1, sA[nt], 0, 0, 0);
            sB[nt] = __builtin_amdgcn_mfma_f32_16x16x32_bf16(kf0, qB0, sB[nt], 0, 0, 0);
            sB[nt] = __builtin_amdgcn_mfma_f32_16x16x32_bf16(kf1, qB1, sB[nt], 0, 0, 0);
        }
        __builtin_amdgcn_s_setprio(0);
    };
    // fixed-reference softmax (m = 0) + PV; pure per-lane VALU, no cross-lane ops
    auto smpv = [&](f32x4 (&s)[4], f32x4& lp, f32x4 (&o)[4],
                    int bi, bool far, float cb, const bf16x8 (&vf)[4][2]) {
        float p[4][4];
        if (far) {
            #pragma unroll
            for (int nt = 0; nt < 4; ++nt)
                #pragma unroll
                for (int r = 0; r < 4; ++r)
                    p[nt][r] = __builtin_amdgcn_exp2f(fmaf(s[nt][r], LOG2E, cb));
        } else {
            #pragma unroll
            for (int nt = 0; nt < 4; ++nt)
                #pragma unroll
                for (int r = 0; r < 4; ++r)
                    p[nt][r] = __builtin_amdgcn_exp2f(fmaf(s[nt][r], LOG2E, LbS[bi + nt * 16 + r]));
        }
        char* pbase = (char*)&Ps[wid][lr][0];
        #pragma unroll
        for (int nt = 0; nt < 4; ++nt) {
            #pragma unroll
            for (int r = 0; r < 4; ++r) lp[r] += p[nt][r];
            bf16x4 pv;
            pv[0] = (__bf16)p[nt][0]; pv[1] = (__bf16)p[nt][1];
            pv[2] = (__bf16)p[nt][2]; pv[3] = (__bf16)p[nt][3];
            *(bf16x4*)(pbase + ((nt * 32 + lg * 8) ^ pxor)) = pv;
        }
        bf16x8 pf0 = *(const bf16x8*)(pbase + ((lg * 16) ^ pxor));
        bf16x8 pf1 = *(const bf16x8*)(pbase + ((64 + lg * 16) ^ pxor));
        __builtin_amdgcn_s_setprio(1);
        #pragma unroll
        for (int dt = 0; dt < 4; ++dt) {
            o[dt] = __builtin_amdgcn_mfma_f32_16x16x32_bf16(vf[dt][0], pf0, o[dt], 0, 0, 0);
            o[dt] = __builtin_amdgcn_mfma_f32_16x16x32_bf16(vf[dt][1], pf1, o[dt], 0, 0, 0);
        }
        __builtin_amdgcn_s_setprio(0);
    };

    bf16x8 vu[4][2], vn[4][2];
    f32x4 sCA[4] = {}, sCB[4] = {};

    // prologue: K(0),K(1) -> LDS; V(0) -> regs
    stageK(0, 0);
    stageK(1, 64);
    loadV(0, vu);
    asm volatile("s_waitcnt vmcnt(8) lgkmcnt(0)" ::: "memory");   // K(0),K(1) landed; V(0) may fly
    __builtin_amdgcn_s_barrier();
    __builtin_amdgcn_sched_barrier(0);
    qk(0, sCA, sCB);                          // QK(0)
    __builtin_amdgcn_s_barrier();             // all waves done reading Ks[0] before iter-0 restages it
    __builtin_amdgcn_sched_barrier(0);

    #pragma unroll 2
    for (int t = 0; t < 32; ++t) {
        const int kt = t * 64;
        const bool even = (t & 1) == 0;
        bf16x8 (&vuse)[4][2] = even ? vu : vn;
        bf16x8 (&vnxt)[4][2] = even ? vn : vu;
        if (t < 31) loadV(kt + 64, vnxt);     // 8 global_load_dwordx4 -> regs
        if (t < 30) stageK(t & 1, kt + 128);  // 2 global_load_lds
        __builtin_amdgcn_sched_barrier(0);    // pin load issue point
        // QK(t+1): independent of softmax(t)
        f32x4 sNA[4] = {}, sNB[4] = {};
        if (t < 31) qk((t + 1) & 1, sNA, sNB);
        // softmax(t) + PV(t)
        const bool far = (kt >= q0b + 256) || (kt + 64 <= q0b - 128);
        const float cb = (kt > q0b) ? cpos : cneg;
        smpv(sCA, lpA, oA, kt + bbA, far, cb, vuse);
        smpv(sCB, lpB, oB, kt + bbB, far, cb, vuse);
        // hand off scores
        #pragma unroll
        for (int nt = 0; nt < 4; ++nt) { sCA[nt] = sNA[nt]; sCB[nt] = sNB[nt]; }
        // end-of-iter: K(t+1) must be landed (issued iter t-1; 10/8 newer loads may fly)
        if (t < 30) {
            asm volatile("s_waitcnt vmcnt(10)" ::: "memory");
            __builtin_amdgcn_s_barrier();
            __builtin_amdgcn_sched_barrier(0);
        } else if (t == 30) {
            asm volatile("s_waitcnt vmcnt(8)" ::: "memory");
            __builtin_amdgcn_s_barrier();
            __builtin_amdgcn_sched_barrier(0);
        }
    }

    // final cross-lane l reduction (4 lanes sharing lr)
    float lA = (lpA[0] + lpA[1]) + (lpA[2] + lpA[3]);
    lA += __shfl_xor(lA, 16); lA += __shfl_xor(lA, 32);
    float lB = (lpB[0] + lpB[1]) + (lpB[2] + lpB[3]);
    lB += __shfl_xor(lB, 16); lB += __shfl_xor(lB, 32);
    // epilogue group A
    {
        float linv = 1.f / lA;
        char* pbase = (char*)&Ps[wid][lr][0];
        #pragma unroll
        for (int dt = 0; dt < 4; ++dt) {
            bf16x4 ov;
            ov[0] = (__bf16)(oA[dt][0] * linv); ov[1] = (__bf16)(oA[dt][1] * linv);
            ov[2] = (__bf16)(oA[dt][2] * linv); ov[3] = (__bf16)(oA[dt][3] * linv);
            *(bf16x4*)(pbase + ((dt * 32 + lg * 8) ^ pxor)) = ov;
        }
        int row = lane >> 2, seg = lane & 3;
        int rxor = (row & 7) << 4;
        char* rbase = (char*)&Ps[wid][row][0];
        uint4 v0 = *(uint4*)(rbase + ((seg * 32) ^ rxor));
        uint4 v1 = *(uint4*)(rbase + ((seg * 32 + 16) ^ rxor));
        ushort_t* dst = Out + (size_t)(b * S_ + q0w + row) * INNER_ + h * DKV_ + seg * 16;
        *(uint4*)&dst[0] = v0;
        *(uint4*)&dst[8] = v1;
    }
    // epilogue group B
    {
        float linv = 1.f / lB;
        char* pbase = (char*)&Ps[wid][lr][0];
        #pragma unroll
        for (int dt = 0; dt < 4; ++dt) {
            bf16x4 ov;
            ov[0] = (__bf16)(oB[dt][0] * linv); ov[1] = (__bf16)(oB[dt][1] * linv);
            ov[2] = (__bf16)(oB[dt][2] * linv); ov[3] = (__bf16)(oB[dt][3] * linv);
            *(bf16x4*)(pbase + ((dt * 32 + lg * 8) ^ pxor)) = ov;
        }
        int row = lane >> 2, seg = lane & 3;
        int rxor = (row & 7) << 4;
        char* rbase = (char*)&Ps[wid][row][0];
        uint4 v0 = *(uint4*)(rbase + ((seg * 32) ^ rxor));
        uint4 v1 = *(uint4*)(rbase + ((seg * 32 + 16) ^ rxor));
        ushort_t* dst = Out + (size_t)(b * S_ + q0w + 16 + row) * INNER_ + h * DKV_ + seg * 16;
        *(uint4*)&dst[0] = v0;
        *(uint4*)&dst[8] = v1;
    }
}

extern "C" void kernel_launch(void* const* d_in, const int* in_sizes, int n_in,
                              void* d_out, int out_size, void* d_ws, size_t ws_size,
                              hipStream_t stream) {
    const float* hs = (const float*)d_in[0];
    const float* wq = (const float*)d_in[1];
    const float* wk = (const float*)d_in[2];
    const float* wv = (const float*)d_in[3];
    const float* wo = (const float*)d_in[4];
    const float* rb = (const float*)d_in[5];

    char* ws = (char*)d_ws;
    unsigned short* Abf = (unsigned short*)(ws);                 // 8 MB  [4096][1024]
    unsigned short* Wqt = (unsigned short*)(ws + (8u  << 20));   // 2 MB  [1024][1024]
    unsigned short* Wkt = (unsigned short*)(ws + (10u << 20));
    unsigned short* Wvt = (unsigned short*)(ws + (12u << 20));
    unsigned short* Wot = (unsigned short*)(ws + (14u << 20));
    unsigned short* Qb  = (unsigned short*)(ws + (16u << 20));   // 8 MB  [b][h][s][64]
    unsigned short* Kb  = (unsigned short*)(ws + (24u << 20));   // 8 MB
    unsigned short* Vtb = (unsigned short*)(ws + (32u << 20));   // 8 MB  [b][h][64][s]
    unsigned short* AOb = (unsigned short*)(ws + (40u << 20));   // 8 MB  [4096][1024]
    float*          Btab = (float*)(ws + (48u << 20));           // 256 KB [16][4096]

    prep_kernel<<<5184, 256, 0, stream>>>(hs, wq, wk, wv, wo, rb,
                                          Abf, Wqt, Wkt, Wvt, Wot, Btab);

    gemm_qkv<<<768, 256, 0, stream>>>(Abf, Wqt, Wkt, Wvt, Qb, Kb, Vtb);

    flash_attn<<<512, 256, 0, stream>>>(Qb, Kb, Vtb, Btab, AOb);

    gemm_out<<<512, 256, 0, stream>>>(AOb, Wot, (float*)d_out);
}